// Round 12
// baseline (604.540 us; speedup 1.0000x reference)
//
#include <hip/hip_runtime.h>
#include <hip/hip_bf16.h>
#include <hip/hip_fp16.h>
#include <cstdint>
#include <cstddef>

#define N_NODES   100000
#define N_EDGES   1600000
#define N_GRAPHS  64
#define HIDDEN    256
#define N_CLASSES 10
#define NEG_SLOPE 0.01f

#define E_PAD    (N_EDGES + 8 * N_NODES)
#define GEMM_BLOCKS 391   // 8 waves each -> 3128 waves, 6250/3128 = 1.9987 strips/wave (balanced)

// counting-sort pipeline geometry (pow2 subranges: sub = d >> 10)
#define PART_EDGES  8192
#define PART_BLOCKS ((N_EDGES + PART_EDGES - 1) / PART_EDGES)  // 196
#define SUB_BITS 10
#define SUB_SIZE 1024
#define N_SUB    ((N_NODES + SUB_SIZE - 1) / SUB_SIZE)          // 98
#define CAP_SUB  17408   // mean 16384, +8 sigma

typedef __attribute__((ext_vector_type(4))) float f32x4;    // MFMA C/D
typedef __attribute__((ext_vector_type(2))) float f32x2;

__device__ __forceinline__ float bf2f(unsigned short u) {
    return __uint_as_float(((unsigned int)u) << 16);
}

// pack one float -> fp8 e4m3 byte (HW cvt)
__device__ __forceinline__ unsigned char f2fp8(float v) {
    return (unsigned char)(__builtin_amdgcn_cvt_pk_fp8_f32(v, v, 0, false) & 0xff);
}

// ---- 4-byte edge record: src in bits [0,17), coef (positive fp16, sign stripped) in bits [17,32) ----
__device__ __forceinline__ unsigned int rec_pack(int s, float c) {
    __half h = __float2half(c);
    unsigned short hb = reinterpret_cast<const __half_raw*>(&h)->x;  // sign bit is 0 (c >= 0)
    return ((unsigned int)hb << 17) | (unsigned int)s;
}
__device__ __forceinline__ float rec_coef(unsigned int u) {
    __half_raw hr; hr.x = (unsigned short)(u >> 17);
    return __half2float(*reinterpret_cast<const __half*>(&hr));  // v_cvt_f32_f16, exact zero for u=0
}

// ---------------- pass A: single-scan subrange partition (counting sort, coarse) ----------------
// bucket entry: bits[0,17)=src, bits[17,27)=dst & 1023
__global__ __launch_bounds__(256) void k_partition(const int* __restrict__ src, const int* __restrict__ dst,
                                                   int* __restrict__ gcur, unsigned int* __restrict__ bucket) {
    __shared__ int lcnt[N_SUB];
    __shared__ int lbase[N_SUB];
    __shared__ int gbase[N_SUB];
    __shared__ unsigned int stage[PART_EDGES];
    int tid = threadIdx.x;
    for (int i = tid; i < N_SUB; i += 256) lcnt[i] = 0;
    __syncthreads();
    int e0 = blockIdx.x * PART_EDGES + tid * 8;
    // phase 1: per-subrange counts (LDS atomics only)
    for (int g = 0; g < 4; ++g) {
        int e = e0 + g * 2048;
        if (e < N_EDGES) {
            int4 da = *(const int4*)(dst + e);
            int4 db = *(const int4*)(dst + e + 4);
            int d[8] = {da.x, da.y, da.z, da.w, db.x, db.y, db.z, db.w};
#pragma unroll
            for (int j = 0; j < 8; ++j) atomicAdd(&lcnt[d[j] >> SUB_BITS], 1);
        }
    }
    __syncthreads();
    if (tid == 0) {
        int s = 0;
        for (int r = 0; r < N_SUB; ++r) { lbase[r] = s; s += lcnt[r]; }
    }
    __syncthreads();
    for (int i = tid; i < N_SUB; i += 256) {
        gbase[i] = atomicAdd(&gcur[i * 16], lcnt[i]);  // padded lines: no false sharing
        lcnt[i] = lbase[i];                            // reuse as write cursor
    }
    __syncthreads();
    // phase 2: scatter into LDS stage, ordered by subrange (reload src/dst: L2-hot)
    for (int g = 0; g < 4; ++g) {
        int e = e0 + g * 2048;
        if (e < N_EDGES) {
            int4 da = *(const int4*)(dst + e);
            int4 db = *(const int4*)(dst + e + 4);
            int4 sa = *(const int4*)(src + e);
            int4 sb = *(const int4*)(src + e + 4);
            int d[8] = {da.x, da.y, da.z, da.w, db.x, db.y, db.z, db.w};
            int s[8] = {sa.x, sa.y, sa.z, sa.w, sb.x, sb.y, sb.z, sb.w};
#pragma unroll
            for (int j = 0; j < 8; ++j) {
                int r = d[j] >> SUB_BITS;
                int p = atomicAdd(&lcnt[r], 1);
                stage[p] = ((unsigned int)(d[j] & (SUB_SIZE - 1)) << 17) | (unsigned int)s[j];
            }
        }
    }
    __syncthreads();
    // coalesced copy-out, segments distributed across waves
    int wv = tid >> 6, ln = tid & 63;
    for (int r = wv; r < N_SUB; r += 4) {
        int base = lbase[r], n = lcnt[r] - base, gb = gbase[r];
        unsigned int* dp = bucket + (size_t)r * CAP_SUB + gb;
        for (int k = ln; k < n; k += 64) dp[k] = stage[base + k];
    }
}

// ---------------- pass B: LDS degree histogram + fused dinv/xpad epilogue ----------------
__global__ __launch_bounds__(512) void k_hist3(const unsigned int* __restrict__ bucket,
                                               const int* __restrict__ gcur, int* __restrict__ cnt,
                                               const float* __restrict__ x,
                                               float* __restrict__ dinv, float4* __restrict__ xp) {
    int sub = blockIdx.x;
    __shared__ int hist[SUB_SIZE];
    for (int i = threadIdx.x; i < SUB_SIZE; i += 512) hist[i] = 0;
    __syncthreads();
    int n = gcur[sub * 16];
    const unsigned int* bp = bucket + (size_t)sub * CAP_SUB;
    for (int i0 = threadIdx.x * 8; i0 < n; i0 += 512 * 8) {
        uint4 ua = *(const uint4*)(bp + i0);
        uint4 ub = *(const uint4*)(bp + i0 + 4);
        unsigned int u[8] = {ua.x, ua.y, ua.z, ua.w, ub.x, ub.y, ub.z, ub.w};
        int m = n - i0; if (m > 8) m = 8;
#pragma unroll
        for (int j = 0; j < 8; ++j) if (j < m) atomicAdd(&hist[u[j] >> 17], 1);
    }
    __syncthreads();
    int base = sub * SUB_SIZE;
    for (int i = threadIdx.x; i < SUB_SIZE; i += 512) {
        int node = base + i;
        if (node < N_NODES) {
            int c = hist[i];
            cnt[node] = c;
            dinv[node] = rsqrtf((float)c + 1.0f);
            xp[node] = make_float4(x[node * 3 + 0], x[node * 3 + 1], x[node * 3 + 2], 0.f);
        }
    }
}

// ---------------- local degree sort: per-1024-subrange counting sort -> perm ----------------
// Used by k_agg3 (thread-per-node): consuming nodes in perm order makes each wave's
// 64 threads have near-equal degree (kills per-thread loop divergence).
__global__ __launch_bounds__(512) void k_locsort(const int* __restrict__ cnt, int* __restrict__ perm) {
    int sub = blockIdx.x, t = threadIdx.x;
    __shared__ int hist[256];
    __shared__ int curs[256];
    if (t < 256) hist[t] = 0;
    __syncthreads();
    int base = sub * SUB_SIZE;
    int i0 = base + t, i1 = base + t + 512;
    int d0 = -1, d1 = -1;
    if (i0 < N_NODES) { d0 = min(cnt[i0], 254); atomicAdd(&hist[d0], 1); }
    if (i1 < N_NODES) { d1 = min(cnt[i1], 254); atomicAdd(&hist[d1], 1); }
    __syncthreads();
    if (t < 256) curs[t] = hist[t];
    __syncthreads();
    for (int off = 1; off < 256; off <<= 1) {
        int v = 0;
        if (t < 256 && t >= off) v = curs[t - off];
        __syncthreads();
        if (t < 256) curs[t] += v;
        __syncthreads();
    }
    if (t < 256) curs[t] -= hist[t];   // exclusive
    __syncthreads();
    if (d0 >= 0) { int p = atomicAdd(&curs[d0], 1); perm[base + p] = i0; }
    if (d1 >= 0) { int p = atomicAdd(&curs[d1], 1); perm[base + p] = i1; }
    int nvalid = N_NODES - base; if (nvalid > SUB_SIZE) nvalid = SUB_SIZE;
    for (int k = nvalid + t; k < SUB_SIZE; k += 512) perm[base + k] = 0x7fffffff;
}

// ---------------- pass C: fill via LDS cursors (preloaded with CSR offsets) -> ZERO global atomics ----------------
__global__ __launch_bounds__(512) void k_fill3(const unsigned int* __restrict__ bucket,
                                               const int* __restrict__ gcur,
                                               const float* __restrict__ dinv,
                                               const int* __restrict__ off,
                                               unsigned int* __restrict__ rec) {
    int sub = blockIdx.x;
    __shared__ int lcur[SUB_SIZE];
    __shared__ float ldv[SUB_SIZE];
    int nb0 = sub * SUB_SIZE;
    for (int i = threadIdx.x; i < SUB_SIZE; i += 512) {
        int node = nb0 + i;
        lcur[i] = (node < N_NODES) ? off[node] : 0;
        ldv[i]  = (node < N_NODES) ? dinv[node] : 0.f;
    }
    __syncthreads();
    int n = gcur[sub * 16];
    const unsigned int* bp = bucket + (size_t)sub * CAP_SUB;
    for (int i0 = threadIdx.x * 8; i0 < n; i0 += 512 * 8) {
        uint4 ua = *(const uint4*)(bp + i0);
        uint4 ub = *(const uint4*)(bp + i0 + 4);
        unsigned int u[8] = {ua.x, ua.y, ua.z, ua.w, ub.x, ub.y, ub.z, ub.w};
        int m = n - i0; if (m > 8) m = 8;
        float ds[8];
#pragma unroll
        for (int j = 0; j < 8; ++j) {
            int s = (j < m) ? (int)(u[j] & 0x1ffff) : 0;
            ds[j] = dinv[s];                         // gathers issued early, independent
        }
#pragma unroll
        for (int j = 0; j < 8; ++j) {
            if (j < m) {
                int dr = (int)(u[j] >> 17);
                float c = ds[j] * ldv[dr];
                int p = atomicAdd(&lcur[dr], 1);     // fast LDS atomic
                rec[p] = rec_pack((int)(u[j] & 0x1ffff), c);
            }
        }
    }
}

// ---------------- graph boundaries via binary search (batch is sorted) ----------------
__global__ void k_graph_bounds(const int* __restrict__ batch,
                               int* __restrict__ gstart, int* __restrict__ gcnt) {
    int g = threadIdx.x;  // 0..63
    int lo = 0, hi = N_NODES;
    while (lo < hi) { int mid = (lo + hi) >> 1; if (batch[mid] < g) lo = mid + 1; else hi = mid; }
    __shared__ int sh[N_GRAPHS + 1];
    sh[g] = lo;
    if (g == 0) sh[N_GRAPHS] = N_NODES;
    __syncthreads();
    gstart[g] = sh[g];
    gcnt[g]   = sh[g + 1] - sh[g];
}

// ---------------- exclusive scan of PADDED degree counts (CSR offsets) ----------------
__global__ void k_scanA(const int* __restrict__ cnt, int* __restrict__ out, int* __restrict__ bsum) {
    __shared__ int sh[256];
    int tid = threadIdx.x;
    int base = blockIdx.x * 1024 + tid * 4;
    int v[4]; int s = 0;
#pragma unroll
    for (int i = 0; i < 4; i++) {
        int idx = base + i;
        v[i] = (idx < N_NODES) ? ((cnt[idx] + 7) & ~7) : 0;
        s += v[i];
    }
    sh[tid] = s; __syncthreads();
    for (int off = 1; off < 256; off <<= 1) {
        int t = (tid >= off) ? sh[tid - off] : 0;
        __syncthreads();
        sh[tid] += t;
        __syncthreads();
    }
    int excl = sh[tid] - s;
    if (tid == 255) bsum[blockIdx.x] = sh[255];
#pragma unroll
    for (int i = 0; i < 4; i++) { int idx = base + i; if (idx < N_NODES) out[idx] = excl; excl += v[i]; }
}

__global__ void k_scanB(int* __restrict__ bsum, int nb) {
    __shared__ int sh[128];
    int tid = threadIdx.x;
    int v = (tid < nb) ? bsum[tid] : 0;
    sh[tid] = v; __syncthreads();
    for (int off = 1; off < 128; off <<= 1) {
        int t = (tid >= off) ? sh[tid - off] : 0;
        __syncthreads();
        sh[tid] += t;
        __syncthreads();
    }
    if (tid < nb) bsum[tid] = sh[tid] - v;  // exclusive
}

// finalize offsets + zero records (src=0, coef=0.0) into padding slots
__global__ void k_scanC(int* __restrict__ off_arr, const int* __restrict__ bsum,
                        const int* __restrict__ cnt, unsigned int* __restrict__ rec) {
    int i = blockIdx.x * 256 + threadIdx.x;
    if (i < N_NODES) {
        int v = off_arr[i] + bsum[i >> 10];
        off_arr[i] = v;
        int c  = cnt[i];
        int cp = (c + 7) & ~7;
        for (int p = v + c; p < v + cp; ++p) rec[p] = 0u;
        if (i == N_NODES - 1) off_arr[N_NODES] = v + cp;
    }
}

// ---------------- weight prep: W[k][n] fp32 -> fp8 in MFMA-fragment-swizzled order ----------------
// one launch handles both W2 and W3 (blockIdx.y selects)
__global__ void k_wprep2(const float* __restrict__ W2, const float* __restrict__ W3,
                         unsigned char* __restrict__ Wz2, unsigned char* __restrict__ Wz3) {
    const float* W = blockIdx.y ? W3 : W2;
    unsigned char* Wswz = blockIdx.y ? Wz3 : Wz2;
    int n = blockIdx.x; int k = threadIdx.x;  // 256 x 256
    unsigned char v = f2fp8(W[k * HIDDEN + n]);
    int k0 = k >> 5, nt = n >> 4;
    int lane = (((k >> 3) & 3) << 4) | (n & 15);
    int j = k & 7;
    Wswz[(size_t)(((k0 * 16) + nt) * 64 + lane) * 8 + j] = v;
}

// ---------------- layer-1 reassociated: ax = Norm * x  (3 features) ----------------
// thread-per-node in PERM (degree-sorted) order: waves have uniform degree -> no divergence
__global__ void k_agg3(const float4* __restrict__ xp, const int* __restrict__ off,
                       const unsigned int* __restrict__ rec, const float* __restrict__ dinv,
                       const int* __restrict__ perm, float4* __restrict__ ax) {
    int gid = blockIdx.x * 256 + threadIdx.x;
    int i = perm[gid];
    if (i >= N_NODES) return;
    float di = dinv[i];
    float selfc = di * di;
    float4 xi = xp[i];
    float a0 = xi.x * selfc, a1 = xi.y * selfc, a2 = xi.z * selfc;
    int e = off[i], e1 = off[i + 1];
    for (; e < e1; e += 4) {
        uint4 rr = *(const uint4*)(rec + e);
        int s0 = rr.x & 0x1ffff, s1 = rr.y & 0x1ffff, s2 = rr.z & 0x1ffff, s3 = rr.w & 0x1ffff;
        float c0 = rec_coef(rr.x), c1 = rec_coef(rr.y), c2 = rec_coef(rr.z), c3 = rec_coef(rr.w);
        float4 x0 = xp[s0], x1 = xp[s1], x2 = xp[s2], x3 = xp[s3];
        a0 += c0 * x0.x + c1 * x1.x + c2 * x2.x + c3 * x3.x;
        a1 += c0 * x0.y + c1 * x1.y + c2 * x2.y + c3 * x3.y;
        a2 += c0 * x0.z + c1 * x1.z + c2 * x2.z + c3 * x3.z;
    }
    ax[i] = make_float4(a0, a1, a2, 0.f);
}

// h1 = leaky(ax @ W1 + b1), fp8 out row-major; W1/b1 staged in LDS, 32 nodes per block
__global__ __launch_bounds__(256) void k_l1(const float4* __restrict__ ax, const float* __restrict__ W1,
                                            const float* __restrict__ b1, unsigned char* __restrict__ out) {
    __shared__ float w0s[HIDDEN], w1s[HIDDEN], w2s[HIDDEN], bbs[HIDDEN];
    int t = threadIdx.x;
    w0s[t] = W1[t]; w1s[t] = W1[HIDDEN + t]; w2s[t] = W1[2 * HIDDEN + t]; bbs[t] = b1[t];
    __syncthreads();
    int base = blockIdx.x * 32;
#pragma unroll 4
    for (int i = 0; i < 32; ++i) {
        int node = base + i;
        if (node >= N_NODES) break;
        float4 a = ax[node];
        float v = a.x * w0s[t] + a.y * w1s[t] + a.z * w2s[t] + bbs[t];
        v = v >= 0.f ? v : NEG_SLOPE * v;
        out[(size_t)node * HIDDEN + t] = f2fp8(v);
    }
}

// ---------------- fp8 MFMA GEMM, SWAPPED operands: D = W^T_tile . A^T ----------------
// STATIC balanced strip loop + LDS-bounce epilogue (r9-proven) + NEXT-STRIP A
// PREFETCH: the 8 A-loads for strip s+STEP issue between the MFMA block and the
// epilogue DS-writes, so their ~500ns latency drains under the epilogue instead
// of serializing the strip loop (GEMM is latency-bound: MfmaUtil 7%, no BW
// ceiling). __launch_bounds__(512,4) pins VGPR <=128 for 2 blocks/CU.
__global__ __launch_bounds__(512, 4) void k_gemm_mfma(const unsigned char* __restrict__ A,
                                                      const unsigned char* __restrict__ Wswz,
                                                      unsigned char* __restrict__ C, int M) {
    __shared__ long Bs[8192];            // 64 KB  W (pre-swizzled fragments)
    __shared__ unsigned int St[8][320];  // 10.25 KB per-wave C staging: 16 rows x 20 dwords (80B, 16B-aligned)
    int tid = threadIdx.x;
    {
        const float4* gsrc = (const float4*)Wswz;
        float4* ldst = (float4*)Bs;
#pragma unroll
        for (int i = 0; i < 8; ++i) ldst[tid + 512 * i] = gsrc[tid + 512 * i];
    }
    __syncthreads();
    int lane = tid & 63, wv = tid >> 6;
    int quad = lane >> 4, r = lane & 15;
    int nstrips = M >> 4;  // 6250
    unsigned int* stw = &St[wv][0];
    int rrow = lane >> 2, rseg = lane & 3;   // read-back/store mapping
    const int STEP = GEMM_BLOCKS * 8;
    int s = blockIdx.x * 8 + wv;             // 3128 waves <= 6250 strips: every wave has >=1
    long af[8];
    {
        const long* Ab = (const long*)(A + (size_t)(s * 16 + r) * HIDDEN) + quad;
#pragma unroll
        for (int k0 = 0; k0 < 8; ++k0) af[k0] = Ab[k0 * 4];
    }
    for (;;) {
        int m0 = s * 16;
        f32x4 acc[16];
#pragma unroll
        for (int i = 0; i < 16; i++) acc[i] = (f32x4){0.f, 0.f, 0.f, 0.f};
#pragma unroll
        for (int k0 = 0; k0 < 8; ++k0) {
#pragma unroll
            for (int nt = 0; nt < 16; ++nt) {
                long w = Bs[(k0 * 16 + nt) * 64 + lane];
                acc[nt] = __builtin_amdgcn_mfma_f32_16x16x32_fp8_fp8(w, af[k0], acc[nt], 0, 0, 0);
            }
        }
        // prefetch next strip's A BEFORE the epilogue (latency hides under DS writes)
        int snext = s + STEP;
        bool more = snext < nstrips;
        long afn[8];
        if (more) {
            const long* Abn = (const long*)(A + (size_t)(snext * 16 + r) * HIDDEN) + quad;
#pragma unroll
            for (int k0 = 0; k0 < 8; ++k0) afn[k0] = Abn[k0 * 4];
        }
        // epilogue: 4 quarters; wave-local LDS bounce -> one dwordx4 per lane per quarter
        // (DS ops are in-order within a wave: write-then-read needs no barrier)
#pragma unroll
        for (int q4 = 0; q4 < 4; ++q4) {
#pragma unroll
            for (int t = 0; t < 4; ++t) {
                f32x4 a = acc[q4 * 4 + t];
                unsigned int pk = __builtin_amdgcn_cvt_pk_fp8_f32(a[0], a[1], 0, false);
                pk = __builtin_amdgcn_cvt_pk_fp8_f32(a[2], a[3], pk, true);
                stw[r * 20 + t * 4 + quad] = pk;   // tile q4*4+t, dword quad of row r
            }
            uint4 v = *(const uint4*)&stw[rrow * 20 + rseg * 4];   // 16B-aligned (80B row stride)
            *(uint4*)(C + (size_t)(m0 + rrow) * HIDDEN + q4 * 64 + rseg * 16) = v;
        }
        if (!more) break;
#pragma unroll
        for (int k0 = 0; k0 < 8; ++k0) af[k0] = afn[k0];
        s = snext;
    }
}

// ---------------- fused aggregation + self-loop + bias + leaky-relu ----------------
// one wave per node; h rows fp8 (256 B); 8 gathers in flight; 4B packed records
__global__ __launch_bounds__(256) void k_agg(const unsigned char* __restrict__ h,
                                             const float* __restrict__ bias,
                                             const int* __restrict__ off, const unsigned int* __restrict__ rec,
                                             const float* __restrict__ dinv,
                                             unsigned char* __restrict__ out) {
    int node = (blockIdx.x * 256 + threadIdx.x) >> 6;
    int lane = threadIdx.x & 63;
    if (node >= N_NODES) return;
    float di = dinv[node];
    float selfc = di * di;
    unsigned int hv = *(const unsigned int*)(h + (size_t)node * HIDDEN + lane * 4);
    f32x2 hlo = __builtin_amdgcn_cvt_pk_f32_fp8(hv, false);
    f32x2 hhi = __builtin_amdgcn_cvt_pk_f32_fp8(hv, true);
    float4 bv = ((const float4*)bias)[lane];
    float4 acc = make_float4(bv.x + hlo.x * selfc, bv.y + hlo.y * selfc,
                             bv.z + hhi.x * selfc, bv.w + hhi.y * selfc);
    int e = off[node], e1 = off[node + 1];
    for (; e < e1; e += 8) {
        uint4 ra = *(const uint4*)(rec + e);
        uint4 rb = *(const uint4*)(rec + e + 4);
        unsigned int w0 = *(const unsigned int*)(h + (size_t)(ra.x & 0x1ffff) * HIDDEN + lane * 4);
        unsigned int w1 = *(const unsigned int*)(h + (size_t)(ra.y & 0x1ffff) * HIDDEN + lane * 4);
        unsigned int w2 = *(const unsigned int*)(h + (size_t)(ra.z & 0x1ffff) * HIDDEN + lane * 4);
        unsigned int w3 = *(const unsigned int*)(h + (size_t)(ra.w & 0x1ffff) * HIDDEN + lane * 4);
        unsigned int w4 = *(const unsigned int*)(h + (size_t)(rb.x & 0x1ffff) * HIDDEN + lane * 4);
        unsigned int w5 = *(const unsigned int*)(h + (size_t)(rb.y & 0x1ffff) * HIDDEN + lane * 4);
        unsigned int w6 = *(const unsigned int*)(h + (size_t)(rb.z & 0x1ffff) * HIDDEN + lane * 4);
        unsigned int w7 = *(const unsigned int*)(h + (size_t)(rb.w & 0x1ffff) * HIDDEN + lane * 4);
        float c0 = rec_coef(ra.x), c1 = rec_coef(ra.y), c2 = rec_coef(ra.z), c3 = rec_coef(ra.w);
        float c4 = rec_coef(rb.x), c5 = rec_coef(rb.y), c6 = rec_coef(rb.z), c7 = rec_coef(rb.w);
        f32x2 l0 = __builtin_amdgcn_cvt_pk_f32_fp8(w0, false), g0 = __builtin_amdgcn_cvt_pk_f32_fp8(w0, true);
        f32x2 l1 = __builtin_amdgcn_cvt_pk_f32_fp8(w1, false), g1 = __builtin_amdgcn_cvt_pk_f32_fp8(w1, true);
        f32x2 l2 = __builtin_amdgcn_cvt_pk_f32_fp8(w2, false), g2 = __builtin_amdgcn_cvt_pk_f32_fp8(w2, true);
        f32x2 l3 = __builtin_amdgcn_cvt_pk_f32_fp8(w3, false), g3 = __builtin_amdgcn_cvt_pk_f32_fp8(w3, true);
        f32x2 l4 = __builtin_amdgcn_cvt_pk_f32_fp8(w4, false), g4 = __builtin_amdgcn_cvt_pk_f32_fp8(w4, true);
        f32x2 l5 = __builtin_amdgcn_cvt_pk_f32_fp8(w5, false), g5 = __builtin_amdgcn_cvt_pk_f32_fp8(w5, true);
        f32x2 l6 = __builtin_amdgcn_cvt_pk_f32_fp8(w6, false), g6 = __builtin_amdgcn_cvt_pk_f32_fp8(w6, true);
        f32x2 l7 = __builtin_amdgcn_cvt_pk_f32_fp8(w7, false), g7 = __builtin_amdgcn_cvt_pk_f32_fp8(w7, true);
        acc.x += c0 * l0.x + c1 * l1.x + c2 * l2.x + c3 * l3.x
               + c4 * l4.x + c5 * l5.x + c6 * l6.x + c7 * l7.x;
        acc.y += c0 * l0.y + c1 * l1.y + c2 * l2.y + c3 * l3.y
               + c4 * l4.y + c5 * l5.y + c6 * l6.y + c7 * l7.y;
        acc.z += c0 * g0.x + c1 * g1.x + c2 * g2.x + c3 * g3.x
               + c4 * g4.x + c5 * g5.x + c6 * g6.x + c7 * g7.x;
        acc.w += c0 * g0.y + c1 * g1.y + c2 * g2.y + c3 * g3.y
               + c4 * g4.y + c5 * g5.y + c6 * g6.y + c7 * g7.y;
    }
    acc.x = acc.x >= 0.f ? acc.x : NEG_SLOPE * acc.x;
    acc.y = acc.y >= 0.f ? acc.y : NEG_SLOPE * acc.y;
    acc.z = acc.z >= 0.f ? acc.z : NEG_SLOPE * acc.z;
    acc.w = acc.w >= 0.f ? acc.w : NEG_SLOPE * acc.w;
    unsigned int pk = __builtin_amdgcn_cvt_pk_fp8_f32(acc.x, acc.y, 0, false);
    pk = __builtin_amdgcn_cvt_pk_fp8_f32(acc.z, acc.w, pk, true);
    *(unsigned int*)(out + (size_t)node * HIDDEN + lane * 4) = pk;
}

// ---------------- global mean pool (partial sums + atomics), fp8 input ----------------
__global__ void k_pool(const unsigned char* __restrict__ h, const int* __restrict__ gstart,
                       const int* __restrict__ gcnt, float* __restrict__ pooled) {
    int g = blockIdx.x, chunk = blockIdx.y, t = threadIdx.x;
    int s = gstart[g], c = gcnt[g];
    int i0 = s + (int)(((long long)c * chunk) / 16);
    int i1 = s + (int)(((long long)c * (chunk + 1)) / 16);
    float acc = 0.f;
    for (int i = i0; i < i1; ++i) {
        f32x2 v = __builtin_amdgcn_cvt_pk_f32_fp8((unsigned int)h[(size_t)i * HIDDEN + t], false);
        acc += v.x;
    }
    atomicAdd(&pooled[g * HIDDEN + t], acc);
}

// ---------------- classifier head + softmax (one wave per graph) ----------------
__global__ void k_head(const float* __restrict__ pooled, const int* __restrict__ gcnt,
                       const float* __restrict__ Wc, const float* __restrict__ bc,
                       float* __restrict__ out) {
    int g = blockIdx.x; int l = threadIdx.x;  // 64 threads
    float inv = 1.0f / fmaxf((float)gcnt[g], 1.0f);
    float p[4];
#pragma unroll
    for (int i = 0; i < 4; i++) p[i] = pooled[g * HIDDEN + l + i * 64] * inv;
    __shared__ float logits[N_CLASSES];
#pragma unroll
    for (int j = 0; j < N_CLASSES; j++) {
        float s = 0.f;
#pragma unroll
        for (int i = 0; i < 4; i++) s += p[i] * Wc[(l + i * 64) * N_CLASSES + j];
        for (int o = 32; o > 0; o >>= 1) s += __shfl_down(s, o, 64);
        if (l == 0) logits[j] = s + bc[j];
    }
    __syncthreads();
    if (l == 0) {
        float m = logits[0];
        for (int j = 1; j < N_CLASSES; j++) m = fmaxf(m, logits[j]);
        float e[N_CLASSES]; float sum = 0.f;
        for (int j = 0; j < N_CLASSES; j++) { e[j] = expf(logits[j] - m); sum += e[j]; }
        for (int j = 0; j < N_CLASSES; j++) out[g * N_CLASSES + j] = e[j] / sum;
    }
}

extern "C" void kernel_launch(void* const* d_in, const int* in_sizes, int n_in,
                              void* d_out, int out_size, void* d_ws, size_t ws_size,
                              hipStream_t stream) {
    const float* x     = (const float*)d_in[0];
    const int*   edge  = (const int*)d_in[1];
    const int*   batch = (const int*)d_in[2];
    const float* W1 = (const float*)d_in[3];
    const float* b1 = (const float*)d_in[4];
    const float* W2 = (const float*)d_in[5];
    const float* b2 = (const float*)d_in[6];
    const float* W3 = (const float*)d_in[7];
    const float* b3 = (const float*)d_in[8];
    const float* Wc = (const float*)d_in[9];
    const float* bc = (const float*)d_in[10];
    float* out = (float*)d_out;
    const int* srcp = edge;
    const int* dstp = edge + N_EDGES;

    char* ws = (char*)d_ws;
    size_t off = 0;
    auto alloc = [&](size_t bytes) -> char* {
        char* p = ws + off;
        off += (bytes + 255) & ~(size_t)255;
        return p;
    };
    unsigned char* hA   = (unsigned char*)alloc((size_t)N_NODES * HIDDEN);  // row-major fp8 (GEMM in)
    unsigned char* hB   = (unsigned char*)alloc((size_t)N_NODES * HIDDEN);  // row-major fp8 (gathered)
    unsigned char* Wz2  = (unsigned char*)alloc((size_t)HIDDEN * HIDDEN);
    unsigned char* Wz3  = (unsigned char*)alloc((size_t)HIDDEN * HIDDEN);
    int*   deg_cnt  = (int*)alloc((size_t)N_NODES * 4);
    float* dinv     = (float*)alloc((size_t)N_NODES * 4);
    int*   csr_off  = (int*)alloc((size_t)(N_NODES + 1) * 4);
    unsigned int* csr_rec = (unsigned int*)alloc((size_t)E_PAD * 4);
    float4* ax      = (float4*)alloc((size_t)N_NODES * 16);
    float4* xp      = (float4*)alloc((size_t)N_NODES * 16);
    int*   gcnt     = (int*)alloc((size_t)N_GRAPHS * 4);
    int*   gstart   = (int*)alloc((size_t)N_GRAPHS * 4);
    float* pooled   = (float*)alloc((size_t)N_GRAPHS * HIDDEN * 4);
    int*   bsum     = (int*)alloc(128 * 4);
    int*   gcur     = (int*)alloc((size_t)N_SUB * 16 * 4);   // 98 cursors, 64B-padded
    int*   perm     = (int*)alloc((size_t)N_SUB * SUB_SIZE * 4);  // degree-sorted node order

    // bucket aliases hB (25.6 MB): 98 x 17408 x 4B = 6.8 MB; hB is first written by
    // k_gemm_mfma, which runs strictly after k_fill3's last bucket read.
    unsigned int* bucket = (unsigned int*)hB;

    hipMemsetAsync(gcur, 0, (size_t)N_SUB * 16 * 4, stream);
    hipMemsetAsync(pooled, 0, (size_t)N_GRAPHS * HIDDEN * 4, stream);

    int nb  = (N_NODES + 255) / 256;
    int sblocks = (N_NODES + 1023) / 1024;  // 98

    // CSR build: partition -> LDS hist (+dinv/xpad fused) -> locsort -> scan -> LDS-cursor fill
    k_partition<<<PART_BLOCKS, 256, 0, stream>>>(srcp, dstp, gcur, bucket);
    k_graph_bounds<<<1, 64, 0, stream>>>(batch, gstart, gcnt);
    k_hist3<<<N_SUB, 512, 0, stream>>>(bucket, gcur, deg_cnt, x, dinv, xp);
    k_locsort<<<N_SUB, 512, 0, stream>>>(deg_cnt, perm);
    k_scanA<<<sblocks, 256, 0, stream>>>(deg_cnt, csr_off, bsum);
    k_scanB<<<1, 128, 0, stream>>>(bsum, sblocks);
    k_scanC<<<nb, 256, 0, stream>>>(csr_off, bsum, deg_cnt, csr_rec);
    k_fill3<<<N_SUB, 512, 0, stream>>>(bucket, gcur, dinv, csr_off, csr_rec);
    dim3 wg(HIDDEN, 2);
    k_wprep2<<<wg, HIDDEN, 0, stream>>>(W2, W3, Wz2, Wz3);

    // layer 1 (reassociated): ax = Norm*x (perm order); h1 = leaky(ax @ W1 + b1) -> hA (fp8)
    k_agg3<<<(N_SUB * SUB_SIZE) / 256, 256, 0, stream>>>(xp, csr_off, csr_rec, dinv, perm, ax);
    k_l1<<<(N_NODES + 31) / 32, 256, 0, stream>>>(ax, W1, b1, hA);

    int aggb = (N_NODES + 3) / 4;
    // layer 2
    k_gemm_mfma<<<GEMM_BLOCKS, 512, 0, stream>>>(hA, Wz2, hB, N_NODES);
    k_agg<<<aggb, 256, 0, stream>>>(hB, b2, csr_off, csr_rec, dinv, hA);
    // layer 3
    k_gemm_mfma<<<GEMM_BLOCKS, 512, 0, stream>>>(hA, Wz3, hB, N_NODES);
    k_agg<<<aggb, 256, 0, stream>>>(hB, b3, csr_off, csr_rec, dinv, hA);
    // pool + head
    dim3 pg(N_GRAPHS, 16);
    k_pool<<<pg, 256, 0, stream>>>(hA, gstart, gcnt, pooled);
    k_head<<<N_GRAPHS, 64, 0, stream>>>(pooled, gcnt, Wc, bc, out);
}

// Round 13
// 445.101 us; speedup vs baseline: 1.3582x; 1.3582x over previous
//
#include <hip/hip_runtime.h>
#include <hip/hip_bf16.h>
#include <hip/hip_fp16.h>
#include <cstdint>
#include <cstddef>

#define N_NODES   100000
#define N_EDGES   1600000
#define N_GRAPHS  64
#define HIDDEN    256
#define N_CLASSES 10
#define NEG_SLOPE 0.01f

#define E_PAD    (N_EDGES + 8 * N_NODES)
#define GEMM_BLOCKS 391   // 8 waves each -> 3128 waves, 6250/3128 = 1.9987 strips/wave (balanced)

// counting-sort pipeline geometry (pow2 subranges: sub = d >> 10)
#define PART_EDGES  8192
#define PART_BLOCKS ((N_EDGES + PART_EDGES - 1) / PART_EDGES)  // 196
#define SUB_BITS 10
#define SUB_SIZE 1024
#define N_SUB    ((N_NODES + SUB_SIZE - 1) / SUB_SIZE)          // 98
#define CAP_SUB  17408   // mean 16384, +8 sigma

typedef __attribute__((ext_vector_type(4))) float f32x4;    // MFMA C/D
typedef __attribute__((ext_vector_type(2))) float f32x2;

__device__ __forceinline__ float bf2f(unsigned short u) {
    return __uint_as_float(((unsigned int)u) << 16);
}

// pack one float -> fp8 e4m3 byte (HW cvt)
__device__ __forceinline__ unsigned char f2fp8(float v) {
    return (unsigned char)(__builtin_amdgcn_cvt_pk_fp8_f32(v, v, 0, false) & 0xff);
}

// ---- 4-byte edge record: src in bits [0,17), coef (positive fp16, sign stripped) in bits [17,32) ----
__device__ __forceinline__ unsigned int rec_pack(int s, float c) {
    __half h = __float2half(c);
    unsigned short hb = reinterpret_cast<const __half_raw*>(&h)->x;  // sign bit is 0 (c >= 0)
    return ((unsigned int)hb << 17) | (unsigned int)s;
}
__device__ __forceinline__ float rec_coef(unsigned int u) {
    __half_raw hr; hr.x = (unsigned short)(u >> 17);
    return __half2float(*reinterpret_cast<const __half*>(&hr));  // v_cvt_f32_f16, exact zero for u=0
}

// ---------------- pass A: single-scan subrange partition (counting sort, coarse) ----------------
// bucket entry: bits[0,17)=src, bits[17,27)=dst & 1023
__global__ __launch_bounds__(256) void k_partition(const int* __restrict__ src, const int* __restrict__ dst,
                                                   int* __restrict__ gcur, unsigned int* __restrict__ bucket) {
    __shared__ int lcnt[N_SUB];
    __shared__ int lbase[N_SUB];
    __shared__ int gbase[N_SUB];
    __shared__ unsigned int stage[PART_EDGES];
    int tid = threadIdx.x;
    for (int i = tid; i < N_SUB; i += 256) lcnt[i] = 0;
    __syncthreads();
    int e0 = blockIdx.x * PART_EDGES + tid * 8;
    // phase 1: per-subrange counts (LDS atomics only)
    for (int g = 0; g < 4; ++g) {
        int e = e0 + g * 2048;
        if (e < N_EDGES) {
            int4 da = *(const int4*)(dst + e);
            int4 db = *(const int4*)(dst + e + 4);
            int d[8] = {da.x, da.y, da.z, da.w, db.x, db.y, db.z, db.w};
#pragma unroll
            for (int j = 0; j < 8; ++j) atomicAdd(&lcnt[d[j] >> SUB_BITS], 1);
        }
    }
    __syncthreads();
    if (tid == 0) {
        int s = 0;
        for (int r = 0; r < N_SUB; ++r) { lbase[r] = s; s += lcnt[r]; }
    }
    __syncthreads();
    for (int i = tid; i < N_SUB; i += 256) {
        gbase[i] = atomicAdd(&gcur[i * 16], lcnt[i]);  // padded lines: no false sharing
        lcnt[i] = lbase[i];                            // reuse as write cursor
    }
    __syncthreads();
    // phase 2: scatter into LDS stage, ordered by subrange (reload src/dst: L2-hot)
    for (int g = 0; g < 4; ++g) {
        int e = e0 + g * 2048;
        if (e < N_EDGES) {
            int4 da = *(const int4*)(dst + e);
            int4 db = *(const int4*)(dst + e + 4);
            int4 sa = *(const int4*)(src + e);
            int4 sb = *(const int4*)(src + e + 4);
            int d[8] = {da.x, da.y, da.z, da.w, db.x, db.y, db.z, db.w};
            int s[8] = {sa.x, sa.y, sa.z, sa.w, sb.x, sb.y, sb.z, sb.w};
#pragma unroll
            for (int j = 0; j < 8; ++j) {
                int r = d[j] >> SUB_BITS;
                int p = atomicAdd(&lcnt[r], 1);
                stage[p] = ((unsigned int)(d[j] & (SUB_SIZE - 1)) << 17) | (unsigned int)s[j];
            }
        }
    }
    __syncthreads();
    // coalesced copy-out, segments distributed across waves
    int wv = tid >> 6, ln = tid & 63;
    for (int r = wv; r < N_SUB; r += 4) {
        int base = lbase[r], n = lcnt[r] - base, gb = gbase[r];
        unsigned int* dp = bucket + (size_t)r * CAP_SUB + gb;
        for (int k = ln; k < n; k += 64) dp[k] = stage[base + k];
    }
}

// ---------------- pass B: LDS degree histogram + fused dinv/xpad + IN-PLACE degree sort ----------------
// The subrange's degree histogram is already in LDS, so the per-subrange counting
// sort (perm for k_agg3 wave-uniformity) runs here too: one fewer launch, no cnt re-read.
__global__ __launch_bounds__(512) void k_hist3(const unsigned int* __restrict__ bucket,
                                               const int* __restrict__ gcur, int* __restrict__ cnt,
                                               const float* __restrict__ x,
                                               float* __restrict__ dinv, float4* __restrict__ xp,
                                               int* __restrict__ perm) {
    int sub = blockIdx.x;
    __shared__ int hist[SUB_SIZE];
    __shared__ int dh[256];
    __shared__ int dcur[256];
    int t = threadIdx.x;
    for (int i = t; i < SUB_SIZE; i += 512) hist[i] = 0;
    if (t < 256) dh[t] = 0;
    __syncthreads();
    int n = gcur[sub * 16];
    const unsigned int* bp = bucket + (size_t)sub * CAP_SUB;
    for (int i0 = t * 8; i0 < n; i0 += 512 * 8) {
        uint4 ua = *(const uint4*)(bp + i0);
        uint4 ub = *(const uint4*)(bp + i0 + 4);
        unsigned int u[8] = {ua.x, ua.y, ua.z, ua.w, ub.x, ub.y, ub.z, ub.w};
        int m = n - i0; if (m > 8) m = 8;
#pragma unroll
        for (int j = 0; j < 8; ++j) if (j < m) atomicAdd(&hist[u[j] >> 17], 1);
    }
    __syncthreads();
    int base = sub * SUB_SIZE;
    for (int i = t; i < SUB_SIZE; i += 512) {
        int node = base + i;
        if (node < N_NODES) {
            int c = hist[i];
            cnt[node] = c;
            dinv[node] = rsqrtf((float)c + 1.0f);
            xp[node] = make_float4(x[node * 3 + 0], x[node * 3 + 1], x[node * 3 + 2], 0.f);
        }
    }
    // ---- fused counting sort by degree (256 bins) ----
    int i0n = base + t, i1n = base + t + 512;
    int d0 = -1, d1 = -1;
    if (i0n < N_NODES) { d0 = min(hist[t], 254); atomicAdd(&dh[d0], 1); }
    if (i1n < N_NODES) { d1 = min(hist[t + 512], 254); atomicAdd(&dh[d1], 1); }
    __syncthreads();
    if (t < 256) dcur[t] = dh[t];
    __syncthreads();
    for (int off = 1; off < 256; off <<= 1) {
        int v = 0;
        if (t < 256 && t >= off) v = dcur[t - off];
        __syncthreads();
        if (t < 256) dcur[t] += v;
        __syncthreads();
    }
    if (t < 256) dcur[t] -= dh[t];   // exclusive
    __syncthreads();
    if (d0 >= 0) { int p = atomicAdd(&dcur[d0], 1); perm[base + p] = i0n; }
    if (d1 >= 0) { int p = atomicAdd(&dcur[d1], 1); perm[base + p] = i1n; }
    int nvalid = N_NODES - base; if (nvalid > SUB_SIZE) nvalid = SUB_SIZE; if (nvalid < 0) nvalid = 0;
    for (int k = nvalid + t; k < SUB_SIZE; k += 512) perm[base + k] = 0x7fffffff;
}

// ---------------- pass C: fill via LDS cursors (preloaded with CSR offsets) -> ZERO global atomics ----------------
__global__ __launch_bounds__(512) void k_fill3(const unsigned int* __restrict__ bucket,
                                               const int* __restrict__ gcur,
                                               const float* __restrict__ dinv,
                                               const int* __restrict__ off,
                                               unsigned int* __restrict__ rec) {
    int sub = blockIdx.x;
    __shared__ int lcur[SUB_SIZE];
    __shared__ float ldv[SUB_SIZE];
    int nb0 = sub * SUB_SIZE;
    for (int i = threadIdx.x; i < SUB_SIZE; i += 512) {
        int node = nb0 + i;
        lcur[i] = (node < N_NODES) ? off[node] : 0;
        ldv[i]  = (node < N_NODES) ? dinv[node] : 0.f;
    }
    __syncthreads();
    int n = gcur[sub * 16];
    const unsigned int* bp = bucket + (size_t)sub * CAP_SUB;
    for (int i0 = threadIdx.x * 8; i0 < n; i0 += 512 * 8) {
        uint4 ua = *(const uint4*)(bp + i0);
        uint4 ub = *(const uint4*)(bp + i0 + 4);
        unsigned int u[8] = {ua.x, ua.y, ua.z, ua.w, ub.x, ub.y, ub.z, ub.w};
        int m = n - i0; if (m > 8) m = 8;
        float ds[8];
#pragma unroll
        for (int j = 0; j < 8; ++j) {
            int s = (j < m) ? (int)(u[j] & 0x1ffff) : 0;
            ds[j] = dinv[s];                         // gathers issued early, independent
        }
#pragma unroll
        for (int j = 0; j < 8; ++j) {
            if (j < m) {
                int dr = (int)(u[j] >> 17);
                float c = ds[j] * ldv[dr];
                int p = atomicAdd(&lcur[dr], 1);     // fast LDS atomic
                rec[p] = rec_pack((int)(u[j] & 0x1ffff), c);
            }
        }
    }
}

// ---------------- graph boundaries via binary search (batch is sorted) ----------------
__global__ void k_graph_bounds(const int* __restrict__ batch,
                               int* __restrict__ gstart, int* __restrict__ gcnt) {
    int g = threadIdx.x;  // 0..63
    int lo = 0, hi = N_NODES;
    while (lo < hi) { int mid = (lo + hi) >> 1; if (batch[mid] < g) lo = mid + 1; else hi = mid; }
    __shared__ int sh[N_GRAPHS + 1];
    sh[g] = lo;
    if (g == 0) sh[N_GRAPHS] = N_NODES;
    __syncthreads();
    gstart[g] = sh[g];
    gcnt[g]   = sh[g + 1] - sh[g];
}

// ---------------- exclusive scan of PADDED degree counts (CSR offsets) ----------------
__global__ void k_scanA(const int* __restrict__ cnt, int* __restrict__ out, int* __restrict__ bsum) {
    __shared__ int sh[256];
    int tid = threadIdx.x;
    int base = blockIdx.x * 1024 + tid * 4;
    int v[4]; int s = 0;
#pragma unroll
    for (int i = 0; i < 4; i++) {
        int idx = base + i;
        v[i] = (idx < N_NODES) ? ((cnt[idx] + 7) & ~7) : 0;
        s += v[i];
    }
    sh[tid] = s; __syncthreads();
    for (int off = 1; off < 256; off <<= 1) {
        int t = (tid >= off) ? sh[tid - off] : 0;
        __syncthreads();
        sh[tid] += t;
        __syncthreads();
    }
    int excl = sh[tid] - s;
    if (tid == 255) bsum[blockIdx.x] = sh[255];
#pragma unroll
    for (int i = 0; i < 4; i++) { int idx = base + i; if (idx < N_NODES) out[idx] = excl; excl += v[i]; }
}

__global__ void k_scanB(int* __restrict__ bsum, int nb) {
    __shared__ int sh[128];
    int tid = threadIdx.x;
    int v = (tid < nb) ? bsum[tid] : 0;
    sh[tid] = v; __syncthreads();
    for (int off = 1; off < 128; off <<= 1) {
        int t = (tid >= off) ? sh[tid - off] : 0;
        __syncthreads();
        sh[tid] += t;
        __syncthreads();
    }
    if (tid < nb) bsum[tid] = sh[tid] - v;  // exclusive
}

// finalize offsets + zero records (src=0, coef=0.0) into padding slots
__global__ void k_scanC(int* __restrict__ off_arr, const int* __restrict__ bsum,
                        const int* __restrict__ cnt, unsigned int* __restrict__ rec) {
    int i = blockIdx.x * 256 + threadIdx.x;
    if (i < N_NODES) {
        int v = off_arr[i] + bsum[i >> 10];
        off_arr[i] = v;
        int c  = cnt[i];
        int cp = (c + 7) & ~7;
        for (int p = v + c; p < v + cp; ++p) rec[p] = 0u;
        if (i == N_NODES - 1) off_arr[N_NODES] = v + cp;
    }
}

// ---------------- weight prep: W[k][n] fp32 -> fp8 in MFMA-fragment-swizzled order ----------------
// one launch handles both W2 and W3 (blockIdx.y selects)
__global__ void k_wprep2(const float* __restrict__ W2, const float* __restrict__ W3,
                         unsigned char* __restrict__ Wz2, unsigned char* __restrict__ Wz3) {
    const float* W = blockIdx.y ? W3 : W2;
    unsigned char* Wswz = blockIdx.y ? Wz3 : Wz2;
    int n = blockIdx.x; int k = threadIdx.x;  // 256 x 256
    unsigned char v = f2fp8(W[k * HIDDEN + n]);
    int k0 = k >> 5, nt = n >> 4;
    int lane = (((k >> 3) & 3) << 4) | (n & 15);
    int j = k & 7;
    Wswz[(size_t)(((k0 * 16) + nt) * 64 + lane) * 8 + j] = v;
}

// ---------------- layer-1 reassociated: ax = Norm * x  (3 features) ----------------
// thread-per-node in PERM (degree-sorted) order: waves have uniform degree -> no divergence
__global__ void k_agg3(const float4* __restrict__ xp, const int* __restrict__ off,
                       const unsigned int* __restrict__ rec, const float* __restrict__ dinv,
                       const int* __restrict__ perm, float4* __restrict__ ax) {
    int gid = blockIdx.x * 256 + threadIdx.x;
    int i = perm[gid];
    if (i >= N_NODES) return;
    float di = dinv[i];
    float selfc = di * di;
    float4 xi = xp[i];
    float a0 = xi.x * selfc, a1 = xi.y * selfc, a2 = xi.z * selfc;
    int e = off[i], e1 = off[i + 1];
    for (; e < e1; e += 4) {
        uint4 rr = *(const uint4*)(rec + e);
        int s0 = rr.x & 0x1ffff, s1 = rr.y & 0x1ffff, s2 = rr.z & 0x1ffff, s3 = rr.w & 0x1ffff;
        float c0 = rec_coef(rr.x), c1 = rec_coef(rr.y), c2 = rec_coef(rr.z), c3 = rec_coef(rr.w);
        float4 x0 = xp[s0], x1 = xp[s1], x2 = xp[s2], x3 = xp[s3];
        a0 += c0 * x0.x + c1 * x1.x + c2 * x2.x + c3 * x3.x;
        a1 += c0 * x0.y + c1 * x1.y + c2 * x2.y + c3 * x3.y;
        a2 += c0 * x0.z + c1 * x1.z + c2 * x2.z + c3 * x3.z;
    }
    ax[i] = make_float4(a0, a1, a2, 0.f);
}

// h1 = leaky(ax @ W1 + b1), fp8 out row-major; W1/b1 staged in LDS, 32 nodes per block
__global__ __launch_bounds__(256) void k_l1(const float4* __restrict__ ax, const float* __restrict__ W1,
                                            const float* __restrict__ b1, unsigned char* __restrict__ out) {
    __shared__ float w0s[HIDDEN], w1s[HIDDEN], w2s[HIDDEN], bbs[HIDDEN];
    int t = threadIdx.x;
    w0s[t] = W1[t]; w1s[t] = W1[HIDDEN + t]; w2s[t] = W1[2 * HIDDEN + t]; bbs[t] = b1[t];
    __syncthreads();
    int base = blockIdx.x * 32;
#pragma unroll 4
    for (int i = 0; i < 32; ++i) {
        int node = base + i;
        if (node >= N_NODES) break;
        float4 a = ax[node];
        float v = a.x * w0s[t] + a.y * w1s[t] + a.z * w2s[t] + bbs[t];
        v = v >= 0.f ? v : NEG_SLOPE * v;
        out[(size_t)node * HIDDEN + t] = f2fp8(v);
    }
}

// ---------------- fp8 MFMA GEMM, SWAPPED operands: D = W^T_tile . A^T ----------------
// STATIC balanced strip loop (3128 waves x ~2 strips) + LDS-bounce epilogue with
// 20-dword row stride (16B-aligned b128 reads) for full-cacheline dwordx4 C stores.
// r9-proven config: 512 threads, 2 blocks/CU, 128 VGPR. (Work-steal atomic, 6-wave,
// and register-prefetch variants all regressed — r4/r11/r12 post-mortems.)
__global__ __launch_bounds__(512, 2) void k_gemm_mfma(const unsigned char* __restrict__ A,
                                                      const unsigned char* __restrict__ Wswz,
                                                      unsigned char* __restrict__ C, int M) {
    __shared__ long Bs[8192];            // 64 KB  W (pre-swizzled fragments)
    __shared__ unsigned int St[8][320];  // 10.25 KB per-wave C staging: 16 rows x 20 dwords (80B, 16B-aligned)
    int tid = threadIdx.x;
    {
        const float4* gsrc = (const float4*)Wswz;
        float4* ldst = (float4*)Bs;
#pragma unroll
        for (int i = 0; i < 8; ++i) ldst[tid + 512 * i] = gsrc[tid + 512 * i];
    }
    __syncthreads();
    int lane = tid & 63, wv = tid >> 6;
    int quad = lane >> 4, r = lane & 15;
    int nstrips = M >> 4;  // 6250
    unsigned int* stw = &St[wv][0];
    int rrow = lane >> 2, rseg = lane & 3;   // read-back/store mapping
    for (int s = blockIdx.x * 8 + wv; s < nstrips; s += GEMM_BLOCKS * 8) {
        int m0 = s * 16;
        const long* Ab = (const long*)(A + (size_t)(m0 + r) * HIDDEN) + quad;
        long af[8];
#pragma unroll
        for (int k0 = 0; k0 < 8; ++k0) af[k0] = Ab[k0 * 4];
        f32x4 acc[16];
#pragma unroll
        for (int i = 0; i < 16; i++) acc[i] = (f32x4){0.f, 0.f, 0.f, 0.f};
#pragma unroll
        for (int k0 = 0; k0 < 8; ++k0) {
#pragma unroll
            for (int nt = 0; nt < 16; ++nt) {
                long w = Bs[(k0 * 16 + nt) * 64 + lane];
                acc[nt] = __builtin_amdgcn_mfma_f32_16x16x32_fp8_fp8(w, af[k0], acc[nt], 0, 0, 0);
            }
        }
        // epilogue: 4 quarters; wave-local LDS bounce -> one dwordx4 per lane per quarter
        // (DS ops are in-order within a wave: write-then-read needs no barrier)
#pragma unroll
        for (int q4 = 0; q4 < 4; ++q4) {
#pragma unroll
            for (int t = 0; t < 4; ++t) {
                f32x4 a = acc[q4 * 4 + t];
                unsigned int pk = __builtin_amdgcn_cvt_pk_fp8_f32(a[0], a[1], 0, false);
                pk = __builtin_amdgcn_cvt_pk_fp8_f32(a[2], a[3], pk, true);
                stw[r * 20 + t * 4 + quad] = pk;   // tile q4*4+t, dword quad of row r
            }
            uint4 v = *(const uint4*)&stw[rrow * 20 + rseg * 4];   // 16B-aligned (80B row stride)
            *(uint4*)(C + (size_t)(m0 + rrow) * HIDDEN + q4 * 64 + rseg * 16) = v;
        }
    }
}

// ---------------- fused aggregation + self-loop + bias + leaky-relu ----------------
// one wave per node; h rows fp8 (256 B); 8 gathers in flight; 4B packed records
__global__ __launch_bounds__(256) void k_agg(const unsigned char* __restrict__ h,
                                             const float* __restrict__ bias,
                                             const int* __restrict__ off, const unsigned int* __restrict__ rec,
                                             const float* __restrict__ dinv,
                                             unsigned char* __restrict__ out) {
    int node = (blockIdx.x * 256 + threadIdx.x) >> 6;
    int lane = threadIdx.x & 63;
    if (node >= N_NODES) return;
    float di = dinv[node];
    float selfc = di * di;
    unsigned int hv = *(const unsigned int*)(h + (size_t)node * HIDDEN + lane * 4);
    f32x2 hlo = __builtin_amdgcn_cvt_pk_f32_fp8(hv, false);
    f32x2 hhi = __builtin_amdgcn_cvt_pk_f32_fp8(hv, true);
    float4 bv = ((const float4*)bias)[lane];
    float4 acc = make_float4(bv.x + hlo.x * selfc, bv.y + hlo.y * selfc,
                             bv.z + hhi.x * selfc, bv.w + hhi.y * selfc);
    int e = off[node], e1 = off[node + 1];
    for (; e < e1; e += 8) {
        uint4 ra = *(const uint4*)(rec + e);
        uint4 rb = *(const uint4*)(rec + e + 4);
        unsigned int w0 = *(const unsigned int*)(h + (size_t)(ra.x & 0x1ffff) * HIDDEN + lane * 4);
        unsigned int w1 = *(const unsigned int*)(h + (size_t)(ra.y & 0x1ffff) * HIDDEN + lane * 4);
        unsigned int w2 = *(const unsigned int*)(h + (size_t)(ra.z & 0x1ffff) * HIDDEN + lane * 4);
        unsigned int w3 = *(const unsigned int*)(h + (size_t)(ra.w & 0x1ffff) * HIDDEN + lane * 4);
        unsigned int w4 = *(const unsigned int*)(h + (size_t)(rb.x & 0x1ffff) * HIDDEN + lane * 4);
        unsigned int w5 = *(const unsigned int*)(h + (size_t)(rb.y & 0x1ffff) * HIDDEN + lane * 4);
        unsigned int w6 = *(const unsigned int*)(h + (size_t)(rb.z & 0x1ffff) * HIDDEN + lane * 4);
        unsigned int w7 = *(const unsigned int*)(h + (size_t)(rb.w & 0x1ffff) * HIDDEN + lane * 4);
        float c0 = rec_coef(ra.x), c1 = rec_coef(ra.y), c2 = rec_coef(ra.z), c3 = rec_coef(ra.w);
        float c4 = rec_coef(rb.x), c5 = rec_coef(rb.y), c6 = rec_coef(rb.z), c7 = rec_coef(rb.w);
        f32x2 l0 = __builtin_amdgcn_cvt_pk_f32_fp8(w0, false), g0 = __builtin_amdgcn_cvt_pk_f32_fp8(w0, true);
        f32x2 l1 = __builtin_amdgcn_cvt_pk_f32_fp8(w1, false), g1 = __builtin_amdgcn_cvt_pk_f32_fp8(w1, true);
        f32x2 l2 = __builtin_amdgcn_cvt_pk_f32_fp8(w2, false), g2 = __builtin_amdgcn_cvt_pk_f32_fp8(w2, true);
        f32x2 l3 = __builtin_amdgcn_cvt_pk_f32_fp8(w3, false), g3 = __builtin_amdgcn_cvt_pk_f32_fp8(w3, true);
        f32x2 l4 = __builtin_amdgcn_cvt_pk_f32_fp8(w4, false), g4 = __builtin_amdgcn_cvt_pk_f32_fp8(w4, true);
        f32x2 l5 = __builtin_amdgcn_cvt_pk_f32_fp8(w5, false), g5 = __builtin_amdgcn_cvt_pk_f32_fp8(w5, true);
        f32x2 l6 = __builtin_amdgcn_cvt_pk_f32_fp8(w6, false), g6 = __builtin_amdgcn_cvt_pk_f32_fp8(w6, true);
        f32x2 l7 = __builtin_amdgcn_cvt_pk_f32_fp8(w7, false), g7 = __builtin_amdgcn_cvt_pk_f32_fp8(w7, true);
        acc.x += c0 * l0.x + c1 * l1.x + c2 * l2.x + c3 * l3.x
               + c4 * l4.x + c5 * l5.x + c6 * l6.x + c7 * l7.x;
        acc.y += c0 * l0.y + c1 * l1.y + c2 * l2.y + c3 * l3.y
               + c4 * l4.y + c5 * l5.y + c6 * l6.y + c7 * l7.y;
        acc.z += c0 * g0.x + c1 * g1.x + c2 * g2.x + c3 * g3.x
               + c4 * g4.x + c5 * g5.x + c6 * g6.x + c7 * g7.x;
        acc.w += c0 * g0.y + c1 * g1.y + c2 * g2.y + c3 * g3.y
               + c4 * g4.y + c5 * g5.y + c6 * g6.y + c7 * g7.y;
    }
    acc.x = acc.x >= 0.f ? acc.x : NEG_SLOPE * acc.x;
    acc.y = acc.y >= 0.f ? acc.y : NEG_SLOPE * acc.y;
    acc.z = acc.z >= 0.f ? acc.z : NEG_SLOPE * acc.z;
    acc.w = acc.w >= 0.f ? acc.w : NEG_SLOPE * acc.w;
    unsigned int pk = __builtin_amdgcn_cvt_pk_fp8_f32(acc.x, acc.y, 0, false);
    pk = __builtin_amdgcn_cvt_pk_fp8_f32(acc.z, acc.w, pk, true);
    *(unsigned int*)(out + (size_t)node * HIDDEN + lane * 4) = pk;
}

// ---------------- global mean pool (partial sums + atomics), fp8 input ----------------
__global__ void k_pool(const unsigned char* __restrict__ h, const int* __restrict__ gstart,
                       const int* __restrict__ gcnt, float* __restrict__ pooled) {
    int g = blockIdx.x, chunk = blockIdx.y, t = threadIdx.x;
    int s = gstart[g], c = gcnt[g];
    int i0 = s + (int)(((long long)c * chunk) / 16);
    int i1 = s + (int)(((long long)c * (chunk + 1)) / 16);
    float acc = 0.f;
    for (int i = i0; i < i1; ++i) {
        f32x2 v = __builtin_amdgcn_cvt_pk_f32_fp8((unsigned int)h[(size_t)i * HIDDEN + t], false);
        acc += v.x;
    }
    atomicAdd(&pooled[g * HIDDEN + t], acc);
}

// ---------------- classifier head + softmax (one wave per graph) ----------------
__global__ void k_head(const float* __restrict__ pooled, const int* __restrict__ gcnt,
                       const float* __restrict__ Wc, const float* __restrict__ bc,
                       float* __restrict__ out) {
    int g = blockIdx.x; int l = threadIdx.x;  // 64 threads
    float inv = 1.0f / fmaxf((float)gcnt[g], 1.0f);
    float p[4];
#pragma unroll
    for (int i = 0; i < 4; i++) p[i] = pooled[g * HIDDEN + l + i * 64] * inv;
    __shared__ float logits[N_CLASSES];
#pragma unroll
    for (int j = 0; j < N_CLASSES; j++) {
        float s = 0.f;
#pragma unroll
        for (int i = 0; i < 4; i++) s += p[i] * Wc[(l + i * 64) * N_CLASSES + j];
        for (int o = 32; o > 0; o >>= 1) s += __shfl_down(s, o, 64);
        if (l == 0) logits[j] = s + bc[j];
    }
    __syncthreads();
    if (l == 0) {
        float m = logits[0];
        for (int j = 1; j < N_CLASSES; j++) m = fmaxf(m, logits[j]);
        float e[N_CLASSES]; float sum = 0.f;
        for (int j = 0; j < N_CLASSES; j++) { e[j] = expf(logits[j] - m); sum += e[j]; }
        for (int j = 0; j < N_CLASSES; j++) out[g * N_CLASSES + j] = e[j] / sum;
    }
}

extern "C" void kernel_launch(void* const* d_in, const int* in_sizes, int n_in,
                              void* d_out, int out_size, void* d_ws, size_t ws_size,
                              hipStream_t stream) {
    const float* x     = (const float*)d_in[0];
    const int*   edge  = (const int*)d_in[1];
    const int*   batch = (const int*)d_in[2];
    const float* W1 = (const float*)d_in[3];
    const float* b1 = (const float*)d_in[4];
    const float* W2 = (const float*)d_in[5];
    const float* b2 = (const float*)d_in[6];
    const float* W3 = (const float*)d_in[7];
    const float* b3 = (const float*)d_in[8];
    const float* Wc = (const float*)d_in[9];
    const float* bc = (const float*)d_in[10];
    float* out = (float*)d_out;
    const int* srcp = edge;
    const int* dstp = edge + N_EDGES;

    char* ws = (char*)d_ws;
    size_t off = 0;
    auto alloc = [&](size_t bytes) -> char* {
        char* p = ws + off;
        off += (bytes + 255) & ~(size_t)255;
        return p;
    };
    unsigned char* hA   = (unsigned char*)alloc((size_t)N_NODES * HIDDEN);  // row-major fp8 (GEMM in)
    unsigned char* hB   = (unsigned char*)alloc((size_t)N_NODES * HIDDEN);  // row-major fp8 (gathered)
    unsigned char* Wz2  = (unsigned char*)alloc((size_t)HIDDEN * HIDDEN);
    unsigned char* Wz3  = (unsigned char*)alloc((size_t)HIDDEN * HIDDEN);
    int*   deg_cnt  = (int*)alloc((size_t)N_NODES * 4);
    float* dinv     = (float*)alloc((size_t)N_NODES * 4);
    int*   csr_off  = (int*)alloc((size_t)(N_NODES + 1) * 4);
    unsigned int* csr_rec = (unsigned int*)alloc((size_t)E_PAD * 4);
    float4* ax      = (float4*)alloc((size_t)N_NODES * 16);
    float4* xp      = (float4*)alloc((size_t)N_NODES * 16);
    int*   gcnt     = (int*)alloc((size_t)N_GRAPHS * 4);
    int*   gstart   = (int*)alloc((size_t)N_GRAPHS * 4);
    float* pooled   = (float*)alloc((size_t)N_GRAPHS * HIDDEN * 4);
    int*   bsum     = (int*)alloc(128 * 4);
    int*   gcur     = (int*)alloc((size_t)N_SUB * 16 * 4);   // 98 cursors, 64B-padded
    int*   perm     = (int*)alloc((size_t)N_SUB * SUB_SIZE * 4);  // degree-sorted node order

    // bucket aliases hB (25.6 MB): 98 x 17408 x 4B = 6.8 MB; hB is first written by
    // k_gemm_mfma, which runs strictly after k_fill3's last bucket read.
    unsigned int* bucket = (unsigned int*)hB;

    hipMemsetAsync(gcur, 0, (size_t)N_SUB * 16 * 4, stream);
    hipMemsetAsync(pooled, 0, (size_t)N_GRAPHS * HIDDEN * 4, stream);

    int nb  = (N_NODES + 255) / 256;
    int sblocks = (N_NODES + 1023) / 1024;  // 98

    // CSR build: partition -> LDS hist (+dinv/xpad+locsort fused) -> scan -> LDS-cursor fill
    k_partition<<<PART_BLOCKS, 256, 0, stream>>>(srcp, dstp, gcur, bucket);
    k_graph_bounds<<<1, 64, 0, stream>>>(batch, gstart, gcnt);
    k_hist3<<<N_SUB, 512, 0, stream>>>(bucket, gcur, deg_cnt, x, dinv, xp, perm);
    k_scanA<<<sblocks, 256, 0, stream>>>(deg_cnt, csr_off, bsum);
    k_scanB<<<1, 128, 0, stream>>>(bsum, sblocks);
    k_scanC<<<nb, 256, 0, stream>>>(csr_off, bsum, deg_cnt, csr_rec);
    k_fill3<<<N_SUB, 512, 0, stream>>>(bucket, gcur, dinv, csr_off, csr_rec);
    dim3 wg(HIDDEN, 2);
    k_wprep2<<<wg, HIDDEN, 0, stream>>>(W2, W3, Wz2, Wz3);

    // layer 1 (reassociated): ax = Norm*x (perm order); h1 = leaky(ax @ W1 + b1) -> hA (fp8)
    k_agg3<<<(N_SUB * SUB_SIZE) / 256, 256, 0, stream>>>(xp, csr_off, csr_rec, dinv, perm, ax);
    k_l1<<<(N_NODES + 31) / 32, 256, 0, stream>>>(ax, W1, b1, hA);

    int aggb = (N_NODES + 3) / 4;
    // layer 2
    k_gemm_mfma<<<GEMM_BLOCKS, 512, 0, stream>>>(hA, Wz2, hB, N_NODES);
    k_agg<<<aggb, 256, 0, stream>>>(hB, b2, csr_off, csr_rec, dinv, hA);
    // layer 3
    k_gemm_mfma<<<GEMM_BLOCKS, 512, 0, stream>>>(hA, Wz3, hB, N_NODES);
    k_agg<<<aggb, 256, 0, stream>>>(hB, b3, csr_off, csr_rec, dinv, hA);
    // pool + head
    dim3 pg(N_GRAPHS, 16);
    k_pool<<<pg, 256, 0, stream>>>(hA, gstart, gcnt, pooled);
    k_head<<<N_GRAPHS, 64, 0, stream>>>(pooled, gcnt, Wc, bc, out);
}

// Round 14
// 442.328 us; speedup vs baseline: 1.3667x; 1.0063x over previous
//
#include <hip/hip_runtime.h>
#include <hip/hip_bf16.h>
#include <hip/hip_fp16.h>
#include <cstdint>
#include <cstddef>

#define N_NODES   100000
#define N_EDGES   1600000
#define N_GRAPHS  64
#define HIDDEN    256
#define N_CLASSES 10
#define NEG_SLOPE 0.01f

#define E_PAD    (N_EDGES + 8 * N_NODES)
#define GEMM_BLOCKS 391   // 8 waves each -> 3128 waves, 6250/3128 = 1.9987 strips/wave (balanced)

// counting-sort pipeline geometry (pow2 subranges: sub = d >> 10)
#define PART_EDGES  8192
#define PART_BLOCKS ((N_EDGES + PART_EDGES - 1) / PART_EDGES)  // 196
#define SUB_BITS 10
#define SUB_SIZE 1024
#define N_SUB    ((N_NODES + SUB_SIZE - 1) / SUB_SIZE)          // 98
#define CAP_SUB  17408   // mean 16384, +8 sigma

typedef __attribute__((ext_vector_type(4))) float f32x4;    // MFMA C/D
typedef __attribute__((ext_vector_type(2))) float f32x2;

__device__ __forceinline__ float bf2f(unsigned short u) {
    return __uint_as_float(((unsigned int)u) << 16);
}

// pack one float -> fp8 e4m3 byte (HW cvt)
__device__ __forceinline__ unsigned char f2fp8(float v) {
    return (unsigned char)(__builtin_amdgcn_cvt_pk_fp8_f32(v, v, 0, false) & 0xff);
}

// ---- 4-byte edge record: src in bits [0,17), coef (positive fp16, sign stripped) in bits [17,32) ----
__device__ __forceinline__ unsigned int rec_pack(int s, float c) {
    __half h = __float2half(c);
    unsigned short hb = reinterpret_cast<const __half_raw*>(&h)->x;  // sign bit is 0 (c >= 0)
    return ((unsigned int)hb << 17) | (unsigned int)s;
}
__device__ __forceinline__ float rec_coef(unsigned int u) {
    __half_raw hr; hr.x = (unsigned short)(u >> 17);
    return __half2float(*reinterpret_cast<const __half*>(&hr));  // v_cvt_f32_f16, exact zero for u=0
}

// lower bound of graph id g in sorted batch array
__device__ __forceinline__ int lb_batch(const int* __restrict__ batch, int g) {
    int lo = 0, hi = N_NODES;
    while (lo < hi) { int mid = (lo + hi) >> 1; if (batch[mid] < g) lo = mid + 1; else hi = mid; }
    return lo;
}

// ---------------- pass A: single-scan subrange partition (counting sort, coarse) ----------------
// bucket entry: bits[0,17)=src, bits[17,27)=dst & 1023
__global__ __launch_bounds__(256) void k_partition(const int* __restrict__ src, const int* __restrict__ dst,
                                                   int* __restrict__ gcur, unsigned int* __restrict__ bucket) {
    __shared__ int lcnt[N_SUB];
    __shared__ int lbase[N_SUB];
    __shared__ int gbase[N_SUB];
    __shared__ unsigned int stage[PART_EDGES];
    int tid = threadIdx.x;
    for (int i = tid; i < N_SUB; i += 256) lcnt[i] = 0;
    __syncthreads();
    int e0 = blockIdx.x * PART_EDGES + tid * 8;
    // phase 1: per-subrange counts (LDS atomics only)
    for (int g = 0; g < 4; ++g) {
        int e = e0 + g * 2048;
        if (e < N_EDGES) {
            int4 da = *(const int4*)(dst + e);
            int4 db = *(const int4*)(dst + e + 4);
            int d[8] = {da.x, da.y, da.z, da.w, db.x, db.y, db.z, db.w};
#pragma unroll
            for (int j = 0; j < 8; ++j) atomicAdd(&lcnt[d[j] >> SUB_BITS], 1);
        }
    }
    __syncthreads();
    if (tid == 0) {
        int s = 0;
        for (int r = 0; r < N_SUB; ++r) { lbase[r] = s; s += lcnt[r]; }
    }
    __syncthreads();
    for (int i = tid; i < N_SUB; i += 256) {
        gbase[i] = atomicAdd(&gcur[i * 16], lcnt[i]);  // padded lines: no false sharing
        lcnt[i] = lbase[i];                            // reuse as write cursor
    }
    __syncthreads();
    // phase 2: scatter into LDS stage, ordered by subrange (reload src/dst: L2-hot)
    for (int g = 0; g < 4; ++g) {
        int e = e0 + g * 2048;
        if (e < N_EDGES) {
            int4 da = *(const int4*)(dst + e);
            int4 db = *(const int4*)(dst + e + 4);
            int4 sa = *(const int4*)(src + e);
            int4 sb = *(const int4*)(src + e + 4);
            int d[8] = {da.x, da.y, da.z, da.w, db.x, db.y, db.z, db.w};
            int s[8] = {sa.x, sa.y, sa.z, sa.w, sb.x, sb.y, sb.z, sb.w};
#pragma unroll
            for (int j = 0; j < 8; ++j) {
                int r = d[j] >> SUB_BITS;
                int p = atomicAdd(&lcnt[r], 1);
                stage[p] = ((unsigned int)(d[j] & (SUB_SIZE - 1)) << 17) | (unsigned int)s[j];
            }
        }
    }
    __syncthreads();
    // coalesced copy-out, segments distributed across waves
    int wv = tid >> 6, ln = tid & 63;
    for (int r = wv; r < N_SUB; r += 4) {
        int base = lbase[r], n = lcnt[r] - base, gb = gbase[r];
        unsigned int* dp = bucket + (size_t)r * CAP_SUB + gb;
        for (int k = ln; k < n; k += 64) dp[k] = stage[base + k];
    }
}

// ---------------- pass B: LDS degree histogram + fused dinv/xpad + IN-PLACE degree sort ----------------
__global__ __launch_bounds__(512) void k_hist3(const unsigned int* __restrict__ bucket,
                                               const int* __restrict__ gcur, int* __restrict__ cnt,
                                               const float* __restrict__ x,
                                               float* __restrict__ dinv, float4* __restrict__ xp,
                                               int* __restrict__ perm) {
    int sub = blockIdx.x;
    __shared__ int hist[SUB_SIZE];
    __shared__ int dh[256];
    __shared__ int dcur[256];
    int t = threadIdx.x;
    for (int i = t; i < SUB_SIZE; i += 512) hist[i] = 0;
    if (t < 256) dh[t] = 0;
    __syncthreads();
    int n = gcur[sub * 16];
    const unsigned int* bp = bucket + (size_t)sub * CAP_SUB;
    for (int i0 = t * 8; i0 < n; i0 += 512 * 8) {
        uint4 ua = *(const uint4*)(bp + i0);
        uint4 ub = *(const uint4*)(bp + i0 + 4);
        unsigned int u[8] = {ua.x, ua.y, ua.z, ua.w, ub.x, ub.y, ub.z, ub.w};
        int m = n - i0; if (m > 8) m = 8;
#pragma unroll
        for (int j = 0; j < 8; ++j) if (j < m) atomicAdd(&hist[u[j] >> 17], 1);
    }
    __syncthreads();
    int base = sub * SUB_SIZE;
    for (int i = t; i < SUB_SIZE; i += 512) {
        int node = base + i;
        if (node < N_NODES) {
            int c = hist[i];
            cnt[node] = c;
            dinv[node] = rsqrtf((float)c + 1.0f);
            xp[node] = make_float4(x[node * 3 + 0], x[node * 3 + 1], x[node * 3 + 2], 0.f);
        }
    }
    // ---- fused counting sort by degree (256 bins) ----
    int i0n = base + t, i1n = base + t + 512;
    int d0 = -1, d1 = -1;
    if (i0n < N_NODES) { d0 = min(hist[t], 254); atomicAdd(&dh[d0], 1); }
    if (i1n < N_NODES) { d1 = min(hist[t + 512], 254); atomicAdd(&dh[d1], 1); }
    __syncthreads();
    if (t < 256) dcur[t] = dh[t];
    __syncthreads();
    for (int off = 1; off < 256; off <<= 1) {
        int v = 0;
        if (t < 256 && t >= off) v = dcur[t - off];
        __syncthreads();
        if (t < 256) dcur[t] += v;
        __syncthreads();
    }
    if (t < 256) dcur[t] -= dh[t];   // exclusive
    __syncthreads();
    if (d0 >= 0) { int p = atomicAdd(&dcur[d0], 1); perm[base + p] = i0n; }
    if (d1 >= 0) { int p = atomicAdd(&dcur[d1], 1); perm[base + p] = i1n; }
    int nvalid = N_NODES - base; if (nvalid > SUB_SIZE) nvalid = SUB_SIZE; if (nvalid < 0) nvalid = 0;
    for (int k = nvalid + t; k < SUB_SIZE; k += 512) perm[base + k] = 0x7fffffff;
}

// ---------------- pass C: fill via LDS cursors (preloaded with CSR offsets) -> ZERO global atomics ----------------
__global__ __launch_bounds__(512) void k_fill3(const unsigned int* __restrict__ bucket,
                                               const int* __restrict__ gcur,
                                               const float* __restrict__ dinv,
                                               const int* __restrict__ off,
                                               unsigned int* __restrict__ rec) {
    int sub = blockIdx.x;
    __shared__ int lcur[SUB_SIZE];
    __shared__ float ldv[SUB_SIZE];
    int nb0 = sub * SUB_SIZE;
    for (int i = threadIdx.x; i < SUB_SIZE; i += 512) {
        int node = nb0 + i;
        lcur[i] = (node < N_NODES) ? off[node] : 0;
        ldv[i]  = (node < N_NODES) ? dinv[node] : 0.f;
    }
    __syncthreads();
    int n = gcur[sub * 16];
    const unsigned int* bp = bucket + (size_t)sub * CAP_SUB;
    for (int i0 = threadIdx.x * 8; i0 < n; i0 += 512 * 8) {
        uint4 ua = *(const uint4*)(bp + i0);
        uint4 ub = *(const uint4*)(bp + i0 + 4);
        unsigned int u[8] = {ua.x, ua.y, ua.z, ua.w, ub.x, ub.y, ub.z, ub.w};
        int m = n - i0; if (m > 8) m = 8;
        float ds[8];
#pragma unroll
        for (int j = 0; j < 8; ++j) {
            int s = (j < m) ? (int)(u[j] & 0x1ffff) : 0;
            ds[j] = dinv[s];                         // gathers issued early, independent
        }
#pragma unroll
        for (int j = 0; j < 8; ++j) {
            if (j < m) {
                int dr = (int)(u[j] >> 17);
                float c = ds[j] * ldv[dr];
                int p = atomicAdd(&lcur[dr], 1);     // fast LDS atomic
                rec[p] = rec_pack((int)(u[j] & 0x1ffff), c);
            }
        }
    }
}

// ---------------- exclusive scan of PADDED degree counts (CSR offsets) ----------------
__global__ void k_scanA(const int* __restrict__ cnt, int* __restrict__ out, int* __restrict__ bsum) {
    __shared__ int sh[256];
    int tid = threadIdx.x;
    int base = blockIdx.x * 1024 + tid * 4;
    int v[4]; int s = 0;
#pragma unroll
    for (int i = 0; i < 4; i++) {
        int idx = base + i;
        v[i] = (idx < N_NODES) ? ((cnt[idx] + 7) & ~7) : 0;
        s += v[i];
    }
    sh[tid] = s; __syncthreads();
    for (int off = 1; off < 256; off <<= 1) {
        int t = (tid >= off) ? sh[tid - off] : 0;
        __syncthreads();
        sh[tid] += t;
        __syncthreads();
    }
    int excl = sh[tid] - s;
    if (tid == 255) bsum[blockIdx.x] = sh[255];
#pragma unroll
    for (int i = 0; i < 4; i++) { int idx = base + i; if (idx < N_NODES) out[idx] = excl; excl += v[i]; }
}

// finalize offsets (inline 98-entry bsum prefix scan — replaces separate scanB launch)
// + init cursor + zero records (src=0, coef=0.0) into padding slots
__global__ void k_scanC(int* __restrict__ off_arr, const int* __restrict__ bsum,
                        const int* __restrict__ cnt, unsigned int* __restrict__ rec) {
    __shared__ int bs[128];
    int tid = threadIdx.x;
    if (tid < 128) bs[tid] = (tid < N_SUB) ? bsum[tid] : 0;
    __syncthreads();
    for (int off = 1; off < 128; off <<= 1) {
        int t = 0;
        if (tid < 128 && tid >= off) t = bs[tid - off];
        __syncthreads();
        if (tid < 128) bs[tid] += t;   // inclusive scan
        __syncthreads();
    }
    int i = blockIdx.x * 256 + tid;
    if (i < N_NODES) {
        int blk = i >> 10;
        int add = blk ? bs[blk - 1] : 0;   // exclusive prefix of block sums
        int v = off_arr[i] + add;
        off_arr[i] = v;
        int c  = cnt[i];
        int cp = (c + 7) & ~7;
        for (int p = v + c; p < v + cp; ++p) rec[p] = 0u;
        if (i == N_NODES - 1) off_arr[N_NODES] = v + cp;
    }
}

// ---------------- weight prep: W[k][n] fp32 -> fp8 in MFMA-fragment-swizzled order ----------------
// one launch handles both W2 and W3 (blockIdx.y selects)
__global__ void k_wprep2(const float* __restrict__ W2, const float* __restrict__ W3,
                         unsigned char* __restrict__ Wz2, unsigned char* __restrict__ Wz3) {
    const float* W = blockIdx.y ? W3 : W2;
    unsigned char* Wswz = blockIdx.y ? Wz3 : Wz2;
    int n = blockIdx.x; int k = threadIdx.x;  // 256 x 256
    unsigned char v = f2fp8(W[k * HIDDEN + n]);
    int k0 = k >> 5, nt = n >> 4;
    int lane = (((k >> 3) & 3) << 4) | (n & 15);
    int j = k & 7;
    Wswz[(size_t)(((k0 * 16) + nt) * 64 + lane) * 8 + j] = v;
}

// ---------------- layer-1 reassociated: ax = Norm * x  (3 features) ----------------
// thread-per-node in PERM (degree-sorted) order: waves have uniform degree -> no divergence
__global__ void k_agg3(const float4* __restrict__ xp, const int* __restrict__ off,
                       const unsigned int* __restrict__ rec, const float* __restrict__ dinv,
                       const int* __restrict__ perm, float4* __restrict__ ax) {
    int gid = blockIdx.x * 256 + threadIdx.x;
    int i = perm[gid];
    if (i >= N_NODES) return;
    float di = dinv[i];
    float selfc = di * di;
    float4 xi = xp[i];
    float a0 = xi.x * selfc, a1 = xi.y * selfc, a2 = xi.z * selfc;
    int e = off[i], e1 = off[i + 1];
    for (; e < e1; e += 4) {
        uint4 rr = *(const uint4*)(rec + e);
        int s0 = rr.x & 0x1ffff, s1 = rr.y & 0x1ffff, s2 = rr.z & 0x1ffff, s3 = rr.w & 0x1ffff;
        float c0 = rec_coef(rr.x), c1 = rec_coef(rr.y), c2 = rec_coef(rr.z), c3 = rec_coef(rr.w);
        float4 x0 = xp[s0], x1 = xp[s1], x2 = xp[s2], x3 = xp[s3];
        a0 += c0 * x0.x + c1 * x1.x + c2 * x2.x + c3 * x3.x;
        a1 += c0 * x0.y + c1 * x1.y + c2 * x2.y + c3 * x3.y;
        a2 += c0 * x0.z + c1 * x1.z + c2 * x2.z + c3 * x3.z;
    }
    ax[i] = make_float4(a0, a1, a2, 0.f);
}

// h1 = leaky(ax @ W1 + b1), fp8 out row-major; W1/b1 staged in LDS, 32 nodes per block
__global__ __launch_bounds__(256) void k_l1(const float4* __restrict__ ax, const float* __restrict__ W1,
                                            const float* __restrict__ b1, unsigned char* __restrict__ out) {
    __shared__ float w0s[HIDDEN], w1s[HIDDEN], w2s[HIDDEN], bbs[HIDDEN];
    int t = threadIdx.x;
    w0s[t] = W1[t]; w1s[t] = W1[HIDDEN + t]; w2s[t] = W1[2 * HIDDEN + t]; bbs[t] = b1[t];
    __syncthreads();
    int base = blockIdx.x * 32;
#pragma unroll 4
    for (int i = 0; i < 32; ++i) {
        int node = base + i;
        if (node >= N_NODES) break;
        float4 a = ax[node];
        float v = a.x * w0s[t] + a.y * w1s[t] + a.z * w2s[t] + bbs[t];
        v = v >= 0.f ? v : NEG_SLOPE * v;
        out[(size_t)node * HIDDEN + t] = f2fp8(v);
    }
}

// ---------------- fp8 MFMA GEMM, SWAPPED operands: D = W^T_tile . A^T ----------------
// STATIC balanced strip loop (3128 waves x ~2 strips) + LDS-bounce epilogue with
// 20-dword row stride (16B-aligned b128 reads) for full-cacheline dwordx4 C stores.
// r9-proven config: 512 threads, 2 blocks/CU, 128 VGPR. (Work-steal atomic, 6-wave,
// and register-prefetch variants all regressed — r4/r11/r12 post-mortems.)
__global__ __launch_bounds__(512, 2) void k_gemm_mfma(const unsigned char* __restrict__ A,
                                                      const unsigned char* __restrict__ Wswz,
                                                      unsigned char* __restrict__ C, int M) {
    __shared__ long Bs[8192];            // 64 KB  W (pre-swizzled fragments)
    __shared__ unsigned int St[8][320];  // 10.25 KB per-wave C staging: 16 rows x 20 dwords (80B, 16B-aligned)
    int tid = threadIdx.x;
    {
        const float4* gsrc = (const float4*)Wswz;
        float4* ldst = (float4*)Bs;
#pragma unroll
        for (int i = 0; i < 8; ++i) ldst[tid + 512 * i] = gsrc[tid + 512 * i];
    }
    __syncthreads();
    int lane = tid & 63, wv = tid >> 6;
    int quad = lane >> 4, r = lane & 15;
    int nstrips = M >> 4;  // 6250
    unsigned int* stw = &St[wv][0];
    int rrow = lane >> 2, rseg = lane & 3;   // read-back/store mapping
    for (int s = blockIdx.x * 8 + wv; s < nstrips; s += GEMM_BLOCKS * 8) {
        int m0 = s * 16;
        const long* Ab = (const long*)(A + (size_t)(m0 + r) * HIDDEN) + quad;
        long af[8];
#pragma unroll
        for (int k0 = 0; k0 < 8; ++k0) af[k0] = Ab[k0 * 4];
        f32x4 acc[16];
#pragma unroll
        for (int i = 0; i < 16; i++) acc[i] = (f32x4){0.f, 0.f, 0.f, 0.f};
#pragma unroll
        for (int k0 = 0; k0 < 8; ++k0) {
#pragma unroll
            for (int nt = 0; nt < 16; ++nt) {
                long w = Bs[(k0 * 16 + nt) * 64 + lane];
                acc[nt] = __builtin_amdgcn_mfma_f32_16x16x32_fp8_fp8(w, af[k0], acc[nt], 0, 0, 0);
            }
        }
        // epilogue: 4 quarters; wave-local LDS bounce -> one dwordx4 per lane per quarter
        // (DS ops are in-order within a wave: write-then-read needs no barrier)
#pragma unroll
        for (int q4 = 0; q4 < 4; ++q4) {
#pragma unroll
            for (int t = 0; t < 4; ++t) {
                f32x4 a = acc[q4 * 4 + t];
                unsigned int pk = __builtin_amdgcn_cvt_pk_fp8_f32(a[0], a[1], 0, false);
                pk = __builtin_amdgcn_cvt_pk_fp8_f32(a[2], a[3], pk, true);
                stw[r * 20 + t * 4 + quad] = pk;   // tile q4*4+t, dword quad of row r
            }
            uint4 v = *(const uint4*)&stw[rrow * 20 + rseg * 4];   // 16B-aligned (80B row stride)
            *(uint4*)(C + (size_t)(m0 + rrow) * HIDDEN + q4 * 64 + rseg * 16) = v;
        }
    }
}

// ---------------- fused aggregation + self-loop + bias + leaky-relu ----------------
// one wave per node; h rows fp8 (256 B); 8 gathers in flight; 4B packed records
__global__ __launch_bounds__(256) void k_agg(const unsigned char* __restrict__ h,
                                             const float* __restrict__ bias,
                                             const int* __restrict__ off, const unsigned int* __restrict__ rec,
                                             const float* __restrict__ dinv,
                                             unsigned char* __restrict__ out) {
    int node = (blockIdx.x * 256 + threadIdx.x) >> 6;
    int lane = threadIdx.x & 63;
    if (node >= N_NODES) return;
    float di = dinv[node];
    float selfc = di * di;
    unsigned int hv = *(const unsigned int*)(h + (size_t)node * HIDDEN + lane * 4);
    f32x2 hlo = __builtin_amdgcn_cvt_pk_f32_fp8(hv, false);
    f32x2 hhi = __builtin_amdgcn_cvt_pk_f32_fp8(hv, true);
    float4 bv = ((const float4*)bias)[lane];
    float4 acc = make_float4(bv.x + hlo.x * selfc, bv.y + hlo.y * selfc,
                             bv.z + hhi.x * selfc, bv.w + hhi.y * selfc);
    int e = off[node], e1 = off[node + 1];
    for (; e < e1; e += 8) {
        uint4 ra = *(const uint4*)(rec + e);
        uint4 rb = *(const uint4*)(rec + e + 4);
        unsigned int w0 = *(const unsigned int*)(h + (size_t)(ra.x & 0x1ffff) * HIDDEN + lane * 4);
        unsigned int w1 = *(const unsigned int*)(h + (size_t)(ra.y & 0x1ffff) * HIDDEN + lane * 4);
        unsigned int w2 = *(const unsigned int*)(h + (size_t)(ra.z & 0x1ffff) * HIDDEN + lane * 4);
        unsigned int w3 = *(const unsigned int*)(h + (size_t)(ra.w & 0x1ffff) * HIDDEN + lane * 4);
        unsigned int w4 = *(const unsigned int*)(h + (size_t)(rb.x & 0x1ffff) * HIDDEN + lane * 4);
        unsigned int w5 = *(const unsigned int*)(h + (size_t)(rb.y & 0x1ffff) * HIDDEN + lane * 4);
        unsigned int w6 = *(const unsigned int*)(h + (size_t)(rb.z & 0x1ffff) * HIDDEN + lane * 4);
        unsigned int w7 = *(const unsigned int*)(h + (size_t)(rb.w & 0x1ffff) * HIDDEN + lane * 4);
        float c0 = rec_coef(ra.x), c1 = rec_coef(ra.y), c2 = rec_coef(ra.z), c3 = rec_coef(ra.w);
        float c4 = rec_coef(rb.x), c5 = rec_coef(rb.y), c6 = rec_coef(rb.z), c7 = rec_coef(rb.w);
        f32x2 l0 = __builtin_amdgcn_cvt_pk_f32_fp8(w0, false), g0 = __builtin_amdgcn_cvt_pk_f32_fp8(w0, true);
        f32x2 l1 = __builtin_amdgcn_cvt_pk_f32_fp8(w1, false), g1 = __builtin_amdgcn_cvt_pk_f32_fp8(w1, true);
        f32x2 l2 = __builtin_amdgcn_cvt_pk_f32_fp8(w2, false), g2 = __builtin_amdgcn_cvt_pk_f32_fp8(w2, true);
        f32x2 l3 = __builtin_amdgcn_cvt_pk_f32_fp8(w3, false), g3 = __builtin_amdgcn_cvt_pk_f32_fp8(w3, true);
        f32x2 l4 = __builtin_amdgcn_cvt_pk_f32_fp8(w4, false), g4 = __builtin_amdgcn_cvt_pk_f32_fp8(w4, true);
        f32x2 l5 = __builtin_amdgcn_cvt_pk_f32_fp8(w5, false), g5 = __builtin_amdgcn_cvt_pk_f32_fp8(w5, true);
        f32x2 l6 = __builtin_amdgcn_cvt_pk_f32_fp8(w6, false), g6 = __builtin_amdgcn_cvt_pk_f32_fp8(w6, true);
        f32x2 l7 = __builtin_amdgcn_cvt_pk_f32_fp8(w7, false), g7 = __builtin_amdgcn_cvt_pk_f32_fp8(w7, true);
        acc.x += c0 * l0.x + c1 * l1.x + c2 * l2.x + c3 * l3.x
               + c4 * l4.x + c5 * l5.x + c6 * l6.x + c7 * l7.x;
        acc.y += c0 * l0.y + c1 * l1.y + c2 * l2.y + c3 * l3.y
               + c4 * l4.y + c5 * l5.y + c6 * l6.y + c7 * l7.y;
        acc.z += c0 * g0.x + c1 * g1.x + c2 * g2.x + c3 * g3.x
               + c4 * g4.x + c5 * g5.x + c6 * g6.x + c7 * g7.x;
        acc.w += c0 * g0.y + c1 * g1.y + c2 * g2.y + c3 * g3.y
               + c4 * g4.y + c5 * g5.y + c6 * g6.y + c7 * g7.y;
    }
    acc.x = acc.x >= 0.f ? acc.x : NEG_SLOPE * acc.x;
    acc.y = acc.y >= 0.f ? acc.y : NEG_SLOPE * acc.y;
    acc.z = acc.z >= 0.f ? acc.z : NEG_SLOPE * acc.z;
    acc.w = acc.w >= 0.f ? acc.w : NEG_SLOPE * acc.w;
    unsigned int pk = __builtin_amdgcn_cvt_pk_fp8_f32(acc.x, acc.y, 0, false);
    pk = __builtin_amdgcn_cvt_pk_fp8_f32(acc.z, acc.w, pk, true);
    *(unsigned int*)(out + (size_t)node * HIDDEN + lane * 4) = pk;
}

// ---------------- global mean pool (partial sums + atomics), fp8 input ----------------
// graph bounds computed inline via binary search on sorted batch (no k_graph_bounds launch)
__global__ void k_pool(const unsigned char* __restrict__ h, const int* __restrict__ batch,
                       float* __restrict__ pooled) {
    int g = blockIdx.x, chunk = blockIdx.y, t = threadIdx.x;
    int s = lb_batch(batch, g);
    int c = lb_batch(batch, g + 1) - s;
    int i0 = s + (int)(((long long)c * chunk) / 16);
    int i1 = s + (int)(((long long)c * (chunk + 1)) / 16);
    float acc = 0.f;
    for (int i = i0; i < i1; ++i) {
        f32x2 v = __builtin_amdgcn_cvt_pk_f32_fp8((unsigned int)h[(size_t)i * HIDDEN + t], false);
        acc += v.x;
    }
    atomicAdd(&pooled[g * HIDDEN + t], acc);
}

// ---------------- classifier head + softmax (one wave per graph) ----------------
__global__ void k_head(const float* __restrict__ pooled, const int* __restrict__ batch,
                       const float* __restrict__ Wc, const float* __restrict__ bc,
                       float* __restrict__ out) {
    int g = blockIdx.x; int l = threadIdx.x;  // 64 threads
    int c = lb_batch(batch, g + 1) - lb_batch(batch, g);
    float inv = 1.0f / fmaxf((float)c, 1.0f);
    float p[4];
#pragma unroll
    for (int i = 0; i < 4; i++) p[i] = pooled[g * HIDDEN + l + i * 64] * inv;
    __shared__ float logits[N_CLASSES];
#pragma unroll
    for (int j = 0; j < N_CLASSES; j++) {
        float s = 0.f;
#pragma unroll
        for (int i = 0; i < 4; i++) s += p[i] * Wc[(l + i * 64) * N_CLASSES + j];
        for (int o = 32; o > 0; o >>= 1) s += __shfl_down(s, o, 64);
        if (l == 0) logits[j] = s + bc[j];
    }
    __syncthreads();
    if (l == 0) {
        float m = logits[0];
        for (int j = 1; j < N_CLASSES; j++) m = fmaxf(m, logits[j]);
        float e[N_CLASSES]; float sum = 0.f;
        for (int j = 0; j < N_CLASSES; j++) { e[j] = expf(logits[j] - m); sum += e[j]; }
        for (int j = 0; j < N_CLASSES; j++) out[g * N_CLASSES + j] = e[j] / sum;
    }
}

extern "C" void kernel_launch(void* const* d_in, const int* in_sizes, int n_in,
                              void* d_out, int out_size, void* d_ws, size_t ws_size,
                              hipStream_t stream) {
    const float* x     = (const float*)d_in[0];
    const int*   edge  = (const int*)d_in[1];
    const int*   batch = (const int*)d_in[2];
    const float* W1 = (const float*)d_in[3];
    const float* b1 = (const float*)d_in[4];
    const float* W2 = (const float*)d_in[5];
    const float* b2 = (const float*)d_in[6];
    const float* W3 = (const float*)d_in[7];
    const float* b3 = (const float*)d_in[8];
    const float* Wc = (const float*)d_in[9];
    const float* bc = (const float*)d_in[10];
    float* out = (float*)d_out;
    const int* srcp = edge;
    const int* dstp = edge + N_EDGES;

    char* ws = (char*)d_ws;
    size_t off = 0;
    auto alloc = [&](size_t bytes) -> char* {
        char* p = ws + off;
        off += (bytes + 255) & ~(size_t)255;
        return p;
    };
    unsigned char* hA   = (unsigned char*)alloc((size_t)N_NODES * HIDDEN);  // row-major fp8 (GEMM in)
    unsigned char* hB   = (unsigned char*)alloc((size_t)N_NODES * HIDDEN);  // row-major fp8 (gathered)
    unsigned char* Wz2  = (unsigned char*)alloc((size_t)HIDDEN * HIDDEN);
    unsigned char* Wz3  = (unsigned char*)alloc((size_t)HIDDEN * HIDDEN);
    int*   deg_cnt  = (int*)alloc((size_t)N_NODES * 4);
    float* dinv     = (float*)alloc((size_t)N_NODES * 4);
    int*   csr_off  = (int*)alloc((size_t)(N_NODES + 1) * 4);
    unsigned int* csr_rec = (unsigned int*)alloc((size_t)E_PAD * 4);
    float4* ax      = (float4*)alloc((size_t)N_NODES * 16);
    float4* xp      = (float4*)alloc((size_t)N_NODES * 16);
    int*   bsum     = (int*)alloc(128 * 4);
    // gcur and pooled allocated ADJACENT so one memset clears both
    int*   gcur     = (int*)alloc((size_t)N_SUB * 16 * 4);   // 98 cursors, 64B-padded (6272 -> 6400)
    float* pooled   = (float*)alloc((size_t)N_GRAPHS * HIDDEN * 4);
    int*   perm     = (int*)alloc((size_t)N_SUB * SUB_SIZE * 4);  // degree-sorted node order

    // bucket aliases hB (25.6 MB): 98 x 17408 x 4B = 6.8 MB; hB is first written by
    // k_gemm_mfma, which runs strictly after k_fill3's last bucket read.
    unsigned int* bucket = (unsigned int*)hB;

    size_t gcur_pad = (((size_t)N_SUB * 16 * 4) + 255) & ~(size_t)255;
    hipMemsetAsync(gcur, 0, gcur_pad + (size_t)N_GRAPHS * HIDDEN * 4, stream);  // gcur + pooled, one call

    int nb  = (N_NODES + 255) / 256;
    int sblocks = (N_NODES + 1023) / 1024;  // 98

    // CSR build: partition -> LDS hist (+dinv/xpad+locsort fused) -> scan (A + fused B/C) -> fill
    k_partition<<<PART_BLOCKS, 256, 0, stream>>>(srcp, dstp, gcur, bucket);
    k_hist3<<<N_SUB, 512, 0, stream>>>(bucket, gcur, deg_cnt, x, dinv, xp, perm);
    k_scanA<<<sblocks, 256, 0, stream>>>(deg_cnt, csr_off, bsum);
    k_scanC<<<nb, 256, 0, stream>>>(csr_off, bsum, deg_cnt, csr_rec);
    k_fill3<<<N_SUB, 512, 0, stream>>>(bucket, gcur, dinv, csr_off, csr_rec);
    dim3 wg(HIDDEN, 2);
    k_wprep2<<<wg, HIDDEN, 0, stream>>>(W2, W3, Wz2, Wz3);

    // layer 1 (reassociated): ax = Norm*x (perm order); h1 = leaky(ax @ W1 + b1) -> hA (fp8)
    k_agg3<<<(N_SUB * SUB_SIZE) / 256, 256, 0, stream>>>(xp, csr_off, csr_rec, dinv, perm, ax);
    k_l1<<<(N_NODES + 31) / 32, 256, 0, stream>>>(ax, W1, b1, hA);

    int aggb = (N_NODES + 3) / 4;
    // layer 2
    k_gemm_mfma<<<GEMM_BLOCKS, 512, 0, stream>>>(hA, Wz2, hB, N_NODES);
    k_agg<<<aggb, 256, 0, stream>>>(hB, b2, csr_off, csr_rec, dinv, hA);
    // layer 3
    k_gemm_mfma<<<GEMM_BLOCKS, 512, 0, stream>>>(hA, Wz3, hB, N_NODES);
    k_agg<<<aggb, 256, 0, stream>>>(hB, b3, csr_off, csr_rec, dinv, hA);
    // pool + head (graph bounds inline via binary search on batch)
    dim3 pg(N_GRAPHS, 16);
    k_pool<<<pg, 256, 0, stream>>>(hA, batch, pooled);
    k_head<<<N_GRAPHS, 64, 0, stream>>>(pooled, batch, Wc, bc, out);
}